// Round 8
// baseline (446.233 us; speedup 1.0000x reference)
//
#include <hip/hip_runtime.h>
#include <stdint.h>

typedef unsigned int u32;
typedef _Float16 f16;
typedef __attribute__((ext_vector_type(8))) _Float16 f16x8;
typedef __attribute__((ext_vector_type(4))) float f32x4;
typedef __attribute__((ext_vector_type(2))) float f32x2;

#define XMS 168   // f16 stride for all LDS rows (336B)

#define NS     524288
#define NBIN   4096
#define NBLK   64
#define SPB    8192      // samples per sort block

// ---- workspace layout (bytes) ----
#define WOFF_WEFF 0u          // 5*32*32*2    = 10240
#define WOFF_W1SW 10240u      // 5*128*32*2   = 40960
#define WOFF_W2SW 51200u      // 4*128*32*2   = 32768
#define WOFF_W3SW 83968u      // 4*16*32*2    = 4096
#define WOFF_VD   88064u      // 48*4         = 192
#define WOFF_TM   131072u     // 3*300*300*64 = 17280000 (fp8)
#define WOFF_H    17411072u   // 64*4096*4    = 1048576
#define WOFF_BT   18459648u   // 4096*64*4    = 1048576
#define WOFF_XS   19508224u   // 524288*24    = 12582912
#define WOFF_PERM 32091136u   // 524288*4     = 2097152
#define WS_NEED   34188288u

#define TBL_SCALE 64.0f
#define TBL_INV   (1.0f/64.0f)

// ================= prep: swizzled f16 weights (1/64 folded) =================
__global__ void prep_k(const float* __restrict__ feat_w,
                       const float* __restrict__ vmc_vec,
                       const float* __restrict__ vmd_vec,
                       const float* __restrict__ w1,
                       const float* __restrict__ w2,
                       const float* __restrict__ w3,
                       f16* __restrict__ Weff, f16* __restrict__ W1sw,
                       f16* __restrict__ W2sw, f16* __restrict__ W3sw,
                       float* __restrict__ vd)
{
  const int N_WEFF = 5120, N_W1 = 20480, N_W2 = 16384, N_W3 = 2048, N_VD = 48;
  const int total = N_WEFF + N_W1 + N_W2 + N_W3 + N_VD;
  for (int t = blockIdx.x*blockDim.x + threadIdx.x; t < total; t += gridDim.x*blockDim.x){
    if (t < N_WEFF){
      int kb = t >> 10, n = (t >> 5) & 31, kk = t & 31, k = kb*32 + kk;
      float v = 0.f;
      if (n < 27 && k < 144)
        v = feat_w[n*144 + k] * 0.5f*(vmc_vec[k*300+149] + vmc_vec[k*300+150]) * TBL_INV;
      Weff[t] = (f16)v;
    } else if (t < N_WEFF + N_W1){
      int u = t - N_WEFF;
      int kb = u >> 12, n = (u >> 5) & 127, kk = u & 31, k = kb*32 + kk;
      W1sw[u] = (f16)((k < 150) ? w1[n*150 + k] : 0.f);
    } else if (t < N_WEFF + N_W1 + N_W2){
      int u = t - N_WEFF - N_W1;
      int kb = u >> 12, n = (u >> 5) & 127, kk = u & 31, k = kb*32 + kk;
      W2sw[u] = (f16)w2[n*128 + k];
    } else if (t < N_WEFF + N_W1 + N_W2 + N_W3){
      int u = t - N_WEFF - N_W1 - N_W2;
      int kb = u >> 9, n = (u >> 5) & 15, kk = u & 31, k = kb*32 + kk;
      W3sw[u] = (f16)((n < 3) ? w3[n*128 + k] : 0.f);
    } else {
      int k = t - N_WEFF - N_W1 - N_W2 - N_W3;
      vd[k] = 0.5f*(vmd_vec[k*300+149] + vmd_vec[k*300+150]) * TBL_INV;
    }
  }
}

// ---- pack feature+density channels into Tm[plane][y][x][64ch] fp8*64 ----
__global__ void pack_k(const float* __restrict__ feat, const float* __restrict__ dens,
                       u32* __restrict__ dst)
{
  __shared__ float tile[48*304];
  int b = blockIdx.x;
  bool isf = b < 900;
  int bb = isf ? b : b - 900;
  int i = bb / 300, y = bb % 300;
  int C = isf ? 48 : 16;
  const float* sp = (isf ? feat : dens) + (size_t)i*C*90000 + (size_t)y*300;
  for (int t = threadIdx.x; t < C*300; t += 256){
    int r = t / 300, x = t - r*300;
    tile[r*304 + x] = sp[(size_t)r*90000 + x] * TBL_SCALE;
  }
  __syncthreads();
  u32* dp = dst + (size_t)(i*300 + y)*300*16 + (isf ? 0 : 12);
  int ng = C >> 2;
  for (int t = threadIdx.x; t < 300*ng; t += 256){
    int x = t / ng, cg = t - x*ng;
    int c = cg*4;
    u32 v = __builtin_amdgcn_cvt_pk_fp8_f32(tile[c*304+x],     tile[(c+1)*304+x], 0, false);
    v     = __builtin_amdgcn_cvt_pk_fp8_f32(tile[(c+2)*304+x], tile[(c+3)*304+x], v, true);
    dp[x*16 + cg] = v;
  }
}

// ================= atomic-free Morton counting sort =================
__device__ __forceinline__ u32 key12(float x, float y, float z){
  int a = min(15, max(0, (int)((x + 1.f)*8.f)));
  int b = min(15, max(0, (int)((y + 1.f)*8.f)));
  int c = min(15, max(0, (int)((z + 1.f)*8.f)));
  u32 r = 0;
#pragma unroll
  for (int i=0;i<4;++i)
    r |= (((u32)(a>>i)&1u)<<(3*i+2)) | (((u32)(b>>i)&1u)<<(3*i+1)) | (((u32)(c>>i)&1u)<<(3*i));
  return r;
}

// per-block LDS histogram -> H[blk][bin]
__global__ __launch_bounds__(256)
void hist_k(const float* __restrict__ xin, u32* __restrict__ H)
{
  __shared__ u32 h[NBIN];
  for (int b = threadIdx.x; b < NBIN; b += 256) h[b] = 0u;
  __syncthreads();
  int base = blockIdx.x * SPB;
#pragma unroll 4
  for (int i = 0; i < SPB/256; ++i){
    int s = base + i*256 + threadIdx.x;
    const float* xp = xin + (size_t)s*6;
    atomicAdd(&h[key12(xp[0], xp[1], xp[2])], 1u);
  }
  __syncthreads();
  u32* Hp = H + (size_t)blockIdx.x*NBIN;
  for (int b = threadIdx.x; b < NBIN; b += 256) Hp[b] = h[b];
}

// scan: Bt[bin*NBLK + blk] = global exclusive base for (blk,bin)
__global__ __launch_bounds__(1024, 1)
void scan_k(const u32* __restrict__ H, u32* __restrict__ Bt)
{
  __shared__ u32 s[1024];
  int t = threadIdx.x;
  u32 T[4], loc[4];
  u32 tot = 0;
#pragma unroll
  for (int j=0;j<4;++j){
    int b = t*4 + j;
    u32 sum = 0;
    for (int k=0;k<NBLK;++k) sum += H[(size_t)k*NBIN + b];
    T[j] = sum; loc[j] = tot; tot += sum;
  }
  s[t] = tot;
  __syncthreads();
  for (int off=1; off<1024; off<<=1){
    u32 v = (t >= off) ? s[t-off] : 0u;
    __syncthreads();
    s[t] += v;
    __syncthreads();
  }
  u32 tbase = (t == 0) ? 0u : s[t-1];
#pragma unroll
  for (int j=0;j<4;++j){
    int b = t*4 + j;
    u32 base = tbase + loc[j];
    u32* bp = Bt + (size_t)b*NBLK;
    for (int k=0;k<NBLK;++k){ bp[k] = base; base += H[(size_t)k*NBIN + b]; }
  }
}

__global__ __launch_bounds__(256)
void scatter_k(const float* __restrict__ xin, const u32* __restrict__ Bt,
               u32* __restrict__ perm, float* __restrict__ xs)
{
  __shared__ u32 cnt[NBIN];
  for (int b = threadIdx.x; b < NBIN; b += 256) cnt[b] = 0u;
  __syncthreads();
  int base = blockIdx.x * SPB;
#pragma unroll 4
  for (int i = 0; i < SPB/256; ++i){
    int s = base + i*256 + threadIdx.x;
    const float* sp = xin + (size_t)s*6;
    float v0=sp[0], v1=sp[1], v2=sp[2], v3=sp[3], v4=sp[4], v5=sp[5];
    u32 k = key12(v0, v1, v2);
    u32 local = atomicAdd(&cnt[k], 1u);
    u32 pos = Bt[(size_t)k*NBLK + blockIdx.x] + local;
    float* dp = xs + (size_t)pos*6;
    dp[0]=v0; dp[1]=v1; dp[2]=v2; dp[3]=v3; dp[4]=v4; dp[5]=v5;
    perm[pos] = (u32)s;
  }
}

__device__ __forceinline__ void decode16(uint4 q, float* o){
  f32x2 t;
  t = __builtin_amdgcn_cvt_pk_f32_fp8(q.x, false); o[0]=t[0];  o[1]=t[1];
  t = __builtin_amdgcn_cvt_pk_f32_fp8(q.x, true ); o[2]=t[0];  o[3]=t[1];
  t = __builtin_amdgcn_cvt_pk_f32_fp8(q.y, false); o[4]=t[0];  o[5]=t[1];
  t = __builtin_amdgcn_cvt_pk_f32_fp8(q.y, true ); o[6]=t[0];  o[7]=t[1];
  t = __builtin_amdgcn_cvt_pk_f32_fp8(q.z, false); o[8]=t[0];  o[9]=t[1];
  t = __builtin_amdgcn_cvt_pk_f32_fp8(q.z, true ); o[10]=t[0]; o[11]=t[1];
  t = __builtin_amdgcn_cvt_pk_f32_fp8(q.w, false); o[12]=t[0]; o[13]=t[1];
  t = __builtin_amdgcn_cvt_pk_f32_fp8(q.w, true ); o[14]=t[0]; o[15]=t[1];
}

// ======== fused main kernel: single LDS buffer in-place, 7 blocks/CU ========
template<bool SORTED>
__global__ __launch_bounds__(256, 7)
void main_k(const float* __restrict__ xs, const u32* __restrict__ perm,
            const f16* __restrict__ WeffSw, const f16* __restrict__ W1sw,
            const f16* __restrict__ W2sw, const f16* __restrict__ W3sw,
            const float* __restrict__ vd,
            const uint4* __restrict__ Tm,
            const float* __restrict__ b1v, const float* __restrict__ b2v,
            const float* __restrict__ b3v, float* __restrict__ out)
{
  // one buffer: Xm -> X (in-place) -> H1 (in-place) -> H2 (in-place)
  __shared__ __align__(16) f16 buf[64*XMS];
  __shared__ float dLds[192];

  const int tid = threadIdx.x;
  const int l = tid & 63;
  const int w = tid >> 6;

  // XCD-chunked swizzle: each XCD owns a contiguous Morton range
  const int tile = SORTED ? ((blockIdx.x & 7)*1024 + (blockIdx.x >> 3)) : blockIdx.x;
  const size_t base = (size_t)tile*64;

  const float* xp = xs + (base + l)*6;
  float p0 = xp[0], p1 = xp[1], p2 = xp[2];

  // output indices (original sample ids)
  u32 pmL = SORTED ? perm[base + l] : (u32)(base + l);
  const int ssb = w*16 + (l>>4)*4;
  u32 pmr[4];
#pragma unroll
  for (int r=0;r<4;++r)
    pmr[r] = SORTED ? perm[base + ssb + r] : (u32)(base + ssb + r);

  // preload dirs for the row this (wave, lane<16) owns in Phase B
  float dd0=0.f, dd1=0.f, dd2=0.f;
  if (l < 16){
    const float* dp = xs + (base + w*16 + l)*6 + 3;
    dd0 = dp[0]; dd1 = dp[1]; dd2 = dp[2];
  }

  // ---------------- Phase A: sampling (waves 0..2, one plane each) ----------------
  if (w < 3){
    float cx = (w==0)? p1 : ((w==1)? p2 : p0);
    float cy = (w==0)? p2 : ((w==1)? p0 : p1);
    float fx = (cx+1.f)*0.5f*299.f, fy = (cy+1.f)*0.5f*299.f;
    float x0f = floorf(fx), y0f = floorf(fy);
    int x0 = min(max((int)x0f,0),299), y0 = min(max((int)y0f,0),299);
    int x1 = min(x0+1,299), y1 = min(y0+1,299);
    float wx = fx-x0f, wy = fy-y0f;
    float w11 = wx*wy, w10 = wy - w11, w01 = wx - w11, w00 = 1.f - wx - wy + w11;

    const uint4* Tb = Tm + (size_t)w*90000*4;
    const uint4* r00 = Tb + (size_t)(y0*300+x0)*4;
    const uint4* r01 = Tb + (size_t)(y0*300+x1)*4;
    const uint4* r10 = Tb + (size_t)(y1*300+x0)*4;
    const uint4* r11 = Tb + (size_t)(y1*300+x1)*4;
    uint4 qa[4], qb[4], qc[4], qd[4];
#pragma unroll
    for (int c4=0;c4<4;++c4){ qa[c4]=r00[c4]; qb[c4]=r01[c4]; qc[c4]=r10[c4]; qd[c4]=r11[c4]; }

    float vdw[16];
#pragma unroll
    for (int j=0;j<16;++j) vdw[j] = vd[w*16 + j];

    f16* dstrow = buf + l*XMS + w*48;
    float dacc = 0.f;
#pragma unroll
    for (int c4=0;c4<4;++c4){
      float A[16],B[16],C[16],D[16];
      decode16(qa[c4],A); decode16(qb[c4],B); decode16(qc[c4],C); decode16(qd[c4],D);
      if (c4 < 3){
        f16x8 o0, o1;
#pragma unroll
        for (int j=0;j<8;++j)
          o0[j] = (f16)(w00*A[j] + w01*B[j] + w10*C[j] + w11*D[j]);
#pragma unroll
        for (int j=0;j<8;++j)
          o1[j] = (f16)(w00*A[8+j] + w01*B[8+j] + w10*C[8+j] + w11*D[8+j]);
        *(f16x8*)(dstrow + c4*16)     = o0;
        *(f16x8*)(dstrow + c4*16 + 8) = o1;
      } else {
#pragma unroll
        for (int j=0;j<16;++j)
          dacc += (w00*A[j] + w01*B[j] + w10*C[j] + w11*D[j]) * vdw[j];
      }
    }
    dLds[w*64 + l] = dacc;
  } else {
    // wave 3: zero K-pad cols [144..160)
    f16x8 z = 0;
    *(f16x8*)(buf + l*XMS + 144) = z;
    *(f16x8*)(buf + l*XMS + 152) = z;
  }
  __syncthreads();

  const int tr = l & 15;
  const int ko = (l >> 4) * 8;

  // ---------------- Phase B: fold MFMA (in-place Xm -> X) + PE ----------------
  {
    if (w == 3){
      float ds = dLds[l] + dLds[64 + l] + dLds[128 + l];
      out[(size_t)pmL*4 + 3] = fmaxf(ds, 0.f);
    }
    f32x4 fa0 = {0.f,0.f,0.f,0.f}, fa1 = {0.f,0.f,0.f,0.f};
    const f16* Arow = buf + (w*16 + tr)*XMS + ko;
#pragma unroll
    for (int kb=0; kb<5; ++kb){
      f16x8 a  = *(const f16x8*)(Arow + kb*32);
      f16x8 b0 = *(const f16x8*)(WeffSw + (size_t)(kb*32 + tr)*32 + ko);
      f16x8 b1 = *(const f16x8*)(WeffSw + (size_t)(kb*32 + 16 + tr)*32 + ko);
      fa0 = __builtin_amdgcn_mfma_f32_16x16x32_f16(a, b0, fa0, 0,0,0);
      fa1 = __builtin_amdgcn_mfma_f32_16x16x32_f16(a, b1, fa1, 0,0,0);
    }
    // pin all X writes after the fold's LDS reads (in-place safety, same-wave rows)
    __builtin_amdgcn_sched_barrier(0);
    asm volatile("" : "+v"(dd0), "+v"(dd1), "+v"(dd2) : "v"(fa0[0]));

#pragma unroll
    for (int nb=0; nb<2; ++nb){
      int f = nb*16 + tr;
      if (f < 27){
#pragma unroll
        for (int r=0;r<4;++r){
          float fv = nb ? fa1[r] : fa0[r];
          f16* Xr = buf + (ssb + r)*XMS;
          Xr[f] = (f16)fv;
          float a1 = 3.14159265358979f*fv;
          float a2 = 6.28318530717959f*fv;
          Xr[30+f]  = (f16)__sinf(a1);
          Xr[57+f]  = (f16)__cosf(a1);
          Xr[84+f]  = (f16)__sinf(a2);
          Xr[111+f] = (f16)__cosf(a2);
        }
      }
    }
    if (l < 16){
      f16* Xr = buf + (w*16 + l)*XMS;
      Xr[27]=(f16)dd0; Xr[28]=(f16)dd1; Xr[29]=(f16)dd2;
      float dv[3]={dd0,dd1,dd2};
#pragma unroll
      for (int j=0;j<3;++j){
        float a1=3.14159265358979f*dv[j], a2=6.28318530717959f*dv[j];
        Xr[138+j]=(f16)__sinf(a1);
        Xr[141+j]=(f16)__cosf(a1);
        Xr[144+j]=(f16)__sinf(a2);
        Xr[147+j]=(f16)__cosf(a2);
      }
    }
  }
  __syncthreads();

  // ---------------- Phase C: layer1 (64x160 * 160x128), H1 overwrites X ----------------
  {
    f32x4 acc[4][2];
#pragma unroll
    for (int m=0;m<4;++m){ acc[m][0]=(f32x4){0.f,0.f,0.f,0.f}; acc[m][1]=(f32x4){0.f,0.f,0.f,0.f}; }
    const int n0 = w*32 + tr;
#pragma unroll
    for (int kb=0; kb<5; ++kb){
      f16x8 b0 = *(const f16x8*)(W1sw + (size_t)(kb*128 + n0)*32 + ko);
      f16x8 b1 = *(const f16x8*)(W1sw + (size_t)(kb*128 + n0 + 16)*32 + ko);
#pragma unroll
      for (int m=0;m<4;++m){
        f16x8 a = *(const f16x8*)(buf + (m*16 + tr)*XMS + kb*32 + ko);
        acc[m][0] = __builtin_amdgcn_mfma_f32_16x16x32_f16(a, b0, acc[m][0], 0,0,0);
        acc[m][1] = __builtin_amdgcn_mfma_f32_16x16x32_f16(a, b1, acc[m][1], 0,0,0);
      }
    }
    __syncthreads();   // all X reads complete before overwriting
    float bb0 = b1v[n0], bb1 = b1v[n0+16];
#pragma unroll
    for (int m=0;m<4;++m){
#pragma unroll
      for (int r=0;r<4;++r){
        int ss = m*16 + (l>>4)*4 + r;
        buf[ss*XMS + n0]      = (f16)fmaxf(acc[m][0][r] + bb0, 0.f);
        buf[ss*XMS + n0 + 16] = (f16)fmaxf(acc[m][1][r] + bb1, 0.f);
      }
    }
  }
  __syncthreads();

  // ---------------- Phase D: layer2 (64x128 * 128x128), H2 overwrites H1 ----------------
  {
    f32x4 acc[4][2];
#pragma unroll
    for (int m=0;m<4;++m){ acc[m][0]=(f32x4){0.f,0.f,0.f,0.f}; acc[m][1]=(f32x4){0.f,0.f,0.f,0.f}; }
    const int n0 = w*32 + tr;
#pragma unroll
    for (int kb=0; kb<4; ++kb){
      f16x8 b0 = *(const f16x8*)(W2sw + (size_t)(kb*128 + n0)*32 + ko);
      f16x8 b1 = *(const f16x8*)(W2sw + (size_t)(kb*128 + n0 + 16)*32 + ko);
#pragma unroll
      for (int m=0;m<4;++m){
        f16x8 a = *(const f16x8*)(buf + (m*16 + tr)*XMS + kb*32 + ko);
        acc[m][0] = __builtin_amdgcn_mfma_f32_16x16x32_f16(a, b0, acc[m][0], 0,0,0);
        acc[m][1] = __builtin_amdgcn_mfma_f32_16x16x32_f16(a, b1, acc[m][1], 0,0,0);
      }
    }
    __syncthreads();   // all H1 reads complete before overwriting
    float bb0 = b2v[n0], bb1 = b2v[n0+16];
#pragma unroll
    for (int m=0;m<4;++m){
#pragma unroll
      for (int r=0;r<4;++r){
        int ss = m*16 + (l>>4)*4 + r;
        buf[ss*XMS + n0]      = (f16)fmaxf(acc[m][0][r] + bb0, 0.f);
        buf[ss*XMS + n0 + 16] = (f16)fmaxf(acc[m][1][r] + bb1, 0.f);
      }
    }
  }
  __syncthreads();

  // ---------------- Phase E: layer3 + sigmoid ----------------
  {
    f32x4 acc = {0.f,0.f,0.f,0.f};
#pragma unroll
    for (int kb=0; kb<4; ++kb){
      f16x8 a = *(const f16x8*)(buf + (w*16 + tr)*XMS + kb*32 + ko);
      f16x8 b = *(const f16x8*)(W3sw + (size_t)(kb*16 + tr)*32 + ko);
      acc = __builtin_amdgcn_mfma_f32_16x16x32_f16(a, b, acc, 0,0,0);
    }
    if (tr < 3){
      float bb = b3v[tr];
#pragma unroll
      for (int r=0;r<4;++r){
        float c = acc[r] + bb;
        out[(size_t)pmr[r]*4 + tr] = 1.f/(1.f + __expf(-c));
      }
    }
  }
}

extern "C" void kernel_launch(void* const* d_in, const int* in_sizes, int n_in,
                              void* d_out, int out_size, void* d_ws, size_t ws_size,
                              hipStream_t stream)
{
  const float* xin     = (const float*)d_in[0];
  const float* vmc_vec = (const float*)d_in[1];
  const float* vmc_mat = (const float*)d_in[2];
  const float* vmd_vec = (const float*)d_in[3];
  const float* vmd_mat = (const float*)d_in[4];
  const float* feat_w  = (const float*)d_in[5];
  const float* w1      = (const float*)d_in[6];
  const float* b1      = (const float*)d_in[7];
  const float* w2      = (const float*)d_in[8];
  const float* b2      = (const float*)d_in[9];
  const float* w3      = (const float*)d_in[10];
  const float* b3      = (const float*)d_in[11];
  float* out = (float*)d_out;

  char* ws = (char*)d_ws;
  f16*   Weff = (f16*)(ws + WOFF_WEFF);
  f16*   W1sw = (f16*)(ws + WOFF_W1SW);
  f16*   W2sw = (f16*)(ws + WOFF_W2SW);
  f16*   W3sw = (f16*)(ws + WOFF_W3SW);
  float* vd   = (float*)(ws + WOFF_VD);
  u32*   Tm   = (u32*)(ws + WOFF_TM);
  u32*   H    = (u32*)(ws + WOFF_H);
  u32*   Bt   = (u32*)(ws + WOFF_BT);
  float* xs   = (float*)(ws + WOFF_XS);
  u32*   perm = (u32*)(ws + WOFF_PERM);

  prep_k<<<64, 256, 0, stream>>>(feat_w, vmc_vec, vmd_vec, w1, w2, w3,
                                 Weff, W1sw, W2sw, W3sw, vd);
  pack_k<<<1800, 256, 0, stream>>>(vmc_mat, vmd_mat, Tm);

  if (ws_size >= (size_t)WS_NEED){
    hist_k<<<NBLK, 256, 0, stream>>>(xin, H);
    scan_k<<<1, 1024, 0, stream>>>(H, Bt);
    scatter_k<<<NBLK, 256, 0, stream>>>(xin, Bt, perm, xs);
    main_k<true><<<8192, 256, 0, stream>>>(xs, perm, Weff, W1sw, W2sw, W3sw, vd,
                                           (const uint4*)Tm, b1, b2, b3, out);
  } else {
    main_k<false><<<8192, 256, 0, stream>>>(xin, nullptr, Weff, W1sw, W2sw, W3sw, vd,
                                            (const uint4*)Tm, b1, b2, b3, out);
  }
}

// Round 9
// 373.632 us; speedup vs baseline: 1.1943x; 1.1943x over previous
//
#include <hip/hip_runtime.h>
#include <stdint.h>

typedef unsigned int u32;
typedef _Float16 f16;
typedef __attribute__((ext_vector_type(8))) _Float16 f16x8;
typedef __attribute__((ext_vector_type(4))) float f32x4;
typedef __attribute__((ext_vector_type(2))) float f32x2;

#define XMS 168   // f16 stride for all LDS rows (336B)

#define NS     524288
#define NBIN   4096
#define NBLK   64
#define SPB    8192      // samples per sort block

// ---- workspace layout (bytes) ----
#define WOFF_WEFF 0u          // 5*32*32*2    = 10240
#define WOFF_W1SW 10240u      // 5*128*32*2   = 40960
#define WOFF_W2SW 51200u      // 4*128*32*2   = 32768
#define WOFF_W3SW 83968u      // 4*16*32*2    = 4096
#define WOFF_VD   88064u      // 48*4         = 192
#define WOFF_TM   131072u     // 3*300*300*64 = 17280000 (fp8)
#define WOFF_HT   17411072u   // 4096*64*4    = 1048576  (transposed hist)
#define WOFF_BT   18459648u   // 4096*64*4    = 1048576
#define WOFF_XS   19508224u   // 524288*24    = 12582912
#define WOFF_PERM 32091136u   // 524288*4     = 2097152
#define WS_NEED   34188288u

#define TBL_SCALE 64.0f
#define TBL_INV   (1.0f/64.0f)

// ================= prep: swizzled f16 weights (1/64 folded) =================
__global__ void prep_k(const float* __restrict__ feat_w,
                       const float* __restrict__ vmc_vec,
                       const float* __restrict__ vmd_vec,
                       const float* __restrict__ w1,
                       const float* __restrict__ w2,
                       const float* __restrict__ w3,
                       f16* __restrict__ Weff, f16* __restrict__ W1sw,
                       f16* __restrict__ W2sw, f16* __restrict__ W3sw,
                       float* __restrict__ vd)
{
  const int N_WEFF = 5120, N_W1 = 20480, N_W2 = 16384, N_W3 = 2048, N_VD = 48;
  const int total = N_WEFF + N_W1 + N_W2 + N_W3 + N_VD;
  for (int t = blockIdx.x*blockDim.x + threadIdx.x; t < total; t += gridDim.x*blockDim.x){
    if (t < N_WEFF){
      int kb = t >> 10, n = (t >> 5) & 31, kk = t & 31, k = kb*32 + kk;
      float v = 0.f;
      if (n < 27 && k < 144)
        v = feat_w[n*144 + k] * 0.5f*(vmc_vec[k*300+149] + vmc_vec[k*300+150]) * TBL_INV;
      Weff[t] = (f16)v;
    } else if (t < N_WEFF + N_W1){
      int u = t - N_WEFF;
      int kb = u >> 12, n = (u >> 5) & 127, kk = u & 31, k = kb*32 + kk;
      W1sw[u] = (f16)((k < 150) ? w1[n*150 + k] : 0.f);
    } else if (t < N_WEFF + N_W1 + N_W2){
      int u = t - N_WEFF - N_W1;
      int kb = u >> 12, n = (u >> 5) & 127, kk = u & 31, k = kb*32 + kk;
      W2sw[u] = (f16)w2[n*128 + k];
    } else if (t < N_WEFF + N_W1 + N_W2 + N_W3){
      int u = t - N_WEFF - N_W1 - N_W2;
      int kb = u >> 9, n = (u >> 5) & 15, kk = u & 31, k = kb*32 + kk;
      W3sw[u] = (f16)((n < 3) ? w3[n*128 + k] : 0.f);
    } else {
      int k = t - N_WEFF - N_W1 - N_W2 - N_W3;
      vd[k] = 0.5f*(vmd_vec[k*300+149] + vmd_vec[k*300+150]) * TBL_INV;
    }
  }
}

// ---- pack feature+density channels into Tm[plane][y][x][64ch] fp8*64 ----
__global__ void pack_k(const float* __restrict__ feat, const float* __restrict__ dens,
                       u32* __restrict__ dst)
{
  __shared__ float tile[48*304];
  int b = blockIdx.x;
  bool isf = b < 900;
  int bb = isf ? b : b - 900;
  int i = bb / 300, y = bb % 300;
  int C = isf ? 48 : 16;
  const float* sp = (isf ? feat : dens) + (size_t)i*C*90000 + (size_t)y*300;
  for (int t = threadIdx.x; t < C*300; t += 256){
    int r = t / 300, x = t - r*300;
    tile[r*304 + x] = sp[(size_t)r*90000 + x] * TBL_SCALE;
  }
  __syncthreads();
  u32* dp = dst + (size_t)(i*300 + y)*300*16 + (isf ? 0 : 12);
  int ng = C >> 2;
  for (int t = threadIdx.x; t < 300*ng; t += 256){
    int x = t / ng, cg = t - x*ng;
    int c = cg*4;
    u32 v = __builtin_amdgcn_cvt_pk_fp8_f32(tile[c*304+x],     tile[(c+1)*304+x], 0, false);
    v     = __builtin_amdgcn_cvt_pk_fp8_f32(tile[(c+2)*304+x], tile[(c+3)*304+x], v, true);
    dp[x*16 + cg] = v;
  }
}

// ================= atomic-free Morton counting sort =================
__device__ __forceinline__ u32 key12(float x, float y, float z){
  int a = min(15, max(0, (int)((x + 1.f)*8.f)));
  int b = min(15, max(0, (int)((y + 1.f)*8.f)));
  int c = min(15, max(0, (int)((z + 1.f)*8.f)));
  u32 r = 0;
#pragma unroll
  for (int i=0;i<4;++i)
    r |= (((u32)(a>>i)&1u)<<(3*i+2)) | (((u32)(b>>i)&1u)<<(3*i+1)) | (((u32)(c>>i)&1u)<<(3*i));
  return r;
}

// per-block LDS histogram -> HT[bin][blk]  (transposed for coalesced scan)
__global__ __launch_bounds__(256)
void hist_k(const float* __restrict__ xin, u32* __restrict__ HT)
{
  __shared__ u32 h[NBIN];
  for (int b = threadIdx.x; b < NBIN; b += 256) h[b] = 0u;
  __syncthreads();
  int base = blockIdx.x * SPB;
#pragma unroll 4
  for (int i = 0; i < SPB/256; ++i){
    int s = base + i*256 + threadIdx.x;
    const float* xp = xin + (size_t)s*6;
    atomicAdd(&h[key12(xp[0], xp[1], xp[2])], 1u);
  }
  __syncthreads();
  for (int b = threadIdx.x; b < NBIN; b += 256)
    HT[(size_t)b*NBLK + blockIdx.x] = h[b];
}

// scan: Bt[bin*NBLK + blk] = global exclusive base for (blk,bin); coalesced reads
__global__ __launch_bounds__(1024, 1)
void scan_k(const u32* __restrict__ HT, u32* __restrict__ Bt)
{
  __shared__ u32 s[1024];
  int t = threadIdx.x;
  u32 tot = 0;
  u32 loc[4];
#pragma unroll
  for (int j=0;j<4;++j){
    int b = t*4 + j;
    loc[j] = tot;
    const u32* hp = HT + (size_t)b*NBLK;
    u32 sum = 0;
#pragma unroll
    for (int k=0;k<NBLK;++k) sum += hp[k];
    tot += sum;
  }
  s[t] = tot;
  __syncthreads();
  for (int off=1; off<1024; off<<=1){
    u32 v = (t >= off) ? s[t-off] : 0u;
    __syncthreads();
    s[t] += v;
    __syncthreads();
  }
  u32 tbase = (t == 0) ? 0u : s[t-1];
#pragma unroll
  for (int j=0;j<4;++j){
    int b = t*4 + j;
    u32 base = tbase + loc[j];
    const u32* hp = HT + (size_t)b*NBLK;
    u32* bp = Bt + (size_t)b*NBLK;
#pragma unroll
    for (int k=0;k<NBLK;++k){ bp[k] = base; base += hp[k]; }
  }
}

__global__ __launch_bounds__(256)
void scatter_k(const float* __restrict__ xin, const u32* __restrict__ Bt,
               u32* __restrict__ perm, float* __restrict__ xs)
{
  __shared__ u32 cnt[NBIN];
  for (int b = threadIdx.x; b < NBIN; b += 256) cnt[b] = 0u;
  __syncthreads();
  int base = blockIdx.x * SPB;
#pragma unroll 4
  for (int i = 0; i < SPB/256; ++i){
    int s = base + i*256 + threadIdx.x;
    const float* sp = xin + (size_t)s*6;
    float v0=sp[0], v1=sp[1], v2=sp[2], v3=sp[3], v4=sp[4], v5=sp[5];
    u32 k = key12(v0, v1, v2);
    u32 local = atomicAdd(&cnt[k], 1u);
    u32 pos = Bt[(size_t)k*NBLK + blockIdx.x] + local;
    float* dp = xs + (size_t)pos*6;
    dp[0]=v0; dp[1]=v1; dp[2]=v2; dp[3]=v3; dp[4]=v4; dp[5]=v5;
    perm[pos] = (u32)s;
  }
}

__device__ __forceinline__ void decode16(uint4 q, float* o){
  f32x2 t;
  t = __builtin_amdgcn_cvt_pk_f32_fp8(q.x, false); o[0]=t[0];  o[1]=t[1];
  t = __builtin_amdgcn_cvt_pk_f32_fp8(q.x, true ); o[2]=t[0];  o[3]=t[1];
  t = __builtin_amdgcn_cvt_pk_f32_fp8(q.y, false); o[4]=t[0];  o[5]=t[1];
  t = __builtin_amdgcn_cvt_pk_f32_fp8(q.y, true ); o[6]=t[0];  o[7]=t[1];
  t = __builtin_amdgcn_cvt_pk_f32_fp8(q.z, false); o[8]=t[0];  o[9]=t[1];
  t = __builtin_amdgcn_cvt_pk_f32_fp8(q.z, true ); o[10]=t[0]; o[11]=t[1];
  t = __builtin_amdgcn_cvt_pk_f32_fp8(q.w, false); o[12]=t[0]; o[13]=t[1];
  t = __builtin_amdgcn_cvt_pk_f32_fp8(q.w, true ); o[14]=t[0]; o[15]=t[1];
}

// ======== fused main kernel: single LDS buffer in-place, 6 blocks/CU ========
template<bool SORTED>
__global__ __launch_bounds__(256, 6)
void main_k(const float* __restrict__ xs, const u32* __restrict__ perm,
            const f16* __restrict__ WeffSw, const f16* __restrict__ W1sw,
            const f16* __restrict__ W2sw, const f16* __restrict__ W3sw,
            const float* __restrict__ vd,
            const uint4* __restrict__ Tm,
            const float* __restrict__ b1v, const float* __restrict__ b2v,
            const float* __restrict__ b3v, float* __restrict__ out)
{
  // one buffer: Xm -> X (in-place) -> H1 (in-place) -> H2 (in-place)
  __shared__ __align__(16) f16 buf[64*XMS];
  __shared__ float dLds[192];

  const int tid = threadIdx.x;
  const int l = tid & 63;
  const int w = tid >> 6;

  // XCD-chunked swizzle: each XCD owns a contiguous Morton range
  const int tile = SORTED ? ((blockIdx.x & 7)*1024 + (blockIdx.x >> 3)) : blockIdx.x;
  const size_t base = (size_t)tile*64;

  const float* xp = xs + (base + l)*6;
  float p0 = xp[0], p1 = xp[1], p2 = xp[2];

  // output indices (original sample ids)
  u32 pmL = SORTED ? perm[base + l] : (u32)(base + l);
  const int ssb = w*16 + (l>>4)*4;
  u32 pmr[4];
#pragma unroll
  for (int r=0;r<4;++r)
    pmr[r] = SORTED ? perm[base + ssb + r] : (u32)(base + ssb + r);

  // preload dirs for the row this (wave, lane<16) owns in Phase B
  float dd0=0.f, dd1=0.f, dd2=0.f;
  if (l < 16){
    const float* dp = xs + (base + w*16 + l)*6 + 3;
    dd0 = dp[0]; dd1 = dp[1]; dd2 = dp[2];
  }

  // ---------------- Phase A: sampling (waves 0..2, one plane each) ----------------
  if (w < 3){
    float cx = (w==0)? p1 : ((w==1)? p2 : p0);
    float cy = (w==0)? p2 : ((w==1)? p0 : p1);
    float fx = (cx+1.f)*0.5f*299.f, fy = (cy+1.f)*0.5f*299.f;
    float x0f = floorf(fx), y0f = floorf(fy);
    int x0 = min(max((int)x0f,0),299), y0 = min(max((int)y0f,0),299);
    int x1 = min(x0+1,299), y1 = min(y0+1,299);
    float wx = fx-x0f, wy = fy-y0f;
    float w11 = wx*wy, w10 = wy - w11, w01 = wx - w11, w00 = 1.f - wx - wy + w11;

    const uint4* Tb = Tm + (size_t)w*90000*4;
    const uint4* r00 = Tb + (size_t)(y0*300+x0)*4;
    const uint4* r01 = Tb + (size_t)(y0*300+x1)*4;
    const uint4* r10 = Tb + (size_t)(y1*300+x0)*4;
    const uint4* r11 = Tb + (size_t)(y1*300+x1)*4;
    uint4 qa[4], qb[4], qc[4], qd[4];
#pragma unroll
    for (int c4=0;c4<4;++c4){ qa[c4]=r00[c4]; qb[c4]=r01[c4]; qc[c4]=r10[c4]; qd[c4]=r11[c4]; }

    float vdw[16];
#pragma unroll
    for (int j=0;j<16;++j) vdw[j] = vd[w*16 + j];

    f16* dstrow = buf + l*XMS + w*48;
    float dacc = 0.f;
#pragma unroll
    for (int c4=0;c4<4;++c4){
      float A[16],B[16],C[16],D[16];
      decode16(qa[c4],A); decode16(qb[c4],B); decode16(qc[c4],C); decode16(qd[c4],D);
      if (c4 < 3){
        f16x8 o0, o1;
#pragma unroll
        for (int j=0;j<8;++j)
          o0[j] = (f16)(w00*A[j] + w01*B[j] + w10*C[j] + w11*D[j]);
#pragma unroll
        for (int j=0;j<8;++j)
          o1[j] = (f16)(w00*A[8+j] + w01*B[8+j] + w10*C[8+j] + w11*D[8+j]);
        *(f16x8*)(dstrow + c4*16)     = o0;
        *(f16x8*)(dstrow + c4*16 + 8) = o1;
      } else {
#pragma unroll
        for (int j=0;j<16;++j)
          dacc += (w00*A[j] + w01*B[j] + w10*C[j] + w11*D[j]) * vdw[j];
      }
    }
    dLds[w*64 + l] = dacc;
  } else {
    // wave 3: zero K-pad cols [144..160)
    f16x8 z = 0;
    *(f16x8*)(buf + l*XMS + 144) = z;
    *(f16x8*)(buf + l*XMS + 152) = z;
  }
  __syncthreads();

  const int tr = l & 15;
  const int ko = (l >> 4) * 8;

  // ---------------- Phase B: fold MFMA (in-place Xm -> X) + PE ----------------
  {
    if (w == 3){
      float ds = dLds[l] + dLds[64 + l] + dLds[128 + l];
      out[(size_t)pmL*4 + 3] = fmaxf(ds, 0.f);
    }
    f32x4 fa0 = {0.f,0.f,0.f,0.f}, fa1 = {0.f,0.f,0.f,0.f};
    const f16* Arow = buf + (w*16 + tr)*XMS + ko;
#pragma unroll
    for (int kb=0; kb<5; ++kb){
      f16x8 a  = *(const f16x8*)(Arow + kb*32);
      f16x8 b0 = *(const f16x8*)(WeffSw + (size_t)(kb*32 + tr)*32 + ko);
      f16x8 b1 = *(const f16x8*)(WeffSw + (size_t)(kb*32 + 16 + tr)*32 + ko);
      fa0 = __builtin_amdgcn_mfma_f32_16x16x32_f16(a, b0, fa0, 0,0,0);
      fa1 = __builtin_amdgcn_mfma_f32_16x16x32_f16(a, b1, fa1, 0,0,0);
    }
    // pin all X writes after the fold's LDS reads (in-place safety, same-wave rows)
    __builtin_amdgcn_sched_barrier(0);
    asm volatile("" : "+v"(dd0), "+v"(dd1), "+v"(dd2) : "v"(fa0[0]));

#pragma unroll
    for (int nb=0; nb<2; ++nb){
      int f = nb*16 + tr;
      if (f < 27){
#pragma unroll
        for (int r=0;r<4;++r){
          float fv = nb ? fa1[r] : fa0[r];
          f16* Xr = buf + (ssb + r)*XMS;
          Xr[f] = (f16)fv;
          float a1 = 3.14159265358979f*fv;
          float a2 = 6.28318530717959f*fv;
          Xr[30+f]  = (f16)__sinf(a1);
          Xr[57+f]  = (f16)__cosf(a1);
          Xr[84+f]  = (f16)__sinf(a2);
          Xr[111+f] = (f16)__cosf(a2);
        }
      }
    }
    if (l < 16){
      f16* Xr = buf + (w*16 + l)*XMS;
      Xr[27]=(f16)dd0; Xr[28]=(f16)dd1; Xr[29]=(f16)dd2;
      float dv[3]={dd0,dd1,dd2};
#pragma unroll
      for (int j=0;j<3;++j){
        float a1=3.14159265358979f*dv[j], a2=6.28318530717959f*dv[j];
        Xr[138+j]=(f16)__sinf(a1);
        Xr[141+j]=(f16)__cosf(a1);
        Xr[144+j]=(f16)__sinf(a2);
        Xr[147+j]=(f16)__cosf(a2);
      }
    }
  }
  __syncthreads();

  // ---------------- Phase C: layer1 (64x160 * 160x128), H1 overwrites X ----------------
  {
    f32x4 acc[4][2];
#pragma unroll
    for (int m=0;m<4;++m){ acc[m][0]=(f32x4){0.f,0.f,0.f,0.f}; acc[m][1]=(f32x4){0.f,0.f,0.f,0.f}; }
    const int n0 = w*32 + tr;
#pragma unroll
    for (int kb=0; kb<5; ++kb){
      f16x8 b0 = *(const f16x8*)(W1sw + (size_t)(kb*128 + n0)*32 + ko);
      f16x8 b1 = *(const f16x8*)(W1sw + (size_t)(kb*128 + n0 + 16)*32 + ko);
#pragma unroll
      for (int m=0;m<4;++m){
        f16x8 a = *(const f16x8*)(buf + (m*16 + tr)*XMS + kb*32 + ko);
        acc[m][0] = __builtin_amdgcn_mfma_f32_16x16x32_f16(a, b0, acc[m][0], 0,0,0);
        acc[m][1] = __builtin_amdgcn_mfma_f32_16x16x32_f16(a, b1, acc[m][1], 0,0,0);
      }
    }
    __syncthreads();   // all X reads complete before overwriting
    float bb0 = b1v[n0], bb1 = b1v[n0+16];
#pragma unroll
    for (int m=0;m<4;++m){
#pragma unroll
      for (int r=0;r<4;++r){
        int ss = m*16 + (l>>4)*4 + r;
        buf[ss*XMS + n0]      = (f16)fmaxf(acc[m][0][r] + bb0, 0.f);
        buf[ss*XMS + n0 + 16] = (f16)fmaxf(acc[m][1][r] + bb1, 0.f);
      }
    }
  }
  __syncthreads();

  // ---------------- Phase D: layer2 (64x128 * 128x128), H2 overwrites H1 ----------------
  {
    f32x4 acc[4][2];
#pragma unroll
    for (int m=0;m<4;++m){ acc[m][0]=(f32x4){0.f,0.f,0.f,0.f}; acc[m][1]=(f32x4){0.f,0.f,0.f,0.f}; }
    const int n0 = w*32 + tr;
#pragma unroll
    for (int kb=0; kb<4; ++kb){
      f16x8 b0 = *(const f16x8*)(W2sw + (size_t)(kb*128 + n0)*32 + ko);
      f16x8 b1 = *(const f16x8*)(W2sw + (size_t)(kb*128 + n0 + 16)*32 + ko);
#pragma unroll
      for (int m=0;m<4;++m){
        f16x8 a = *(const f16x8*)(buf + (m*16 + tr)*XMS + kb*32 + ko);
        acc[m][0] = __builtin_amdgcn_mfma_f32_16x16x32_f16(a, b0, acc[m][0], 0,0,0);
        acc[m][1] = __builtin_amdgcn_mfma_f32_16x16x32_f16(a, b1, acc[m][1], 0,0,0);
      }
    }
    __syncthreads();   // all H1 reads complete before overwriting
    float bb0 = b2v[n0], bb1 = b2v[n0+16];
#pragma unroll
    for (int m=0;m<4;++m){
#pragma unroll
      for (int r=0;r<4;++r){
        int ss = m*16 + (l>>4)*4 + r;
        buf[ss*XMS + n0]      = (f16)fmaxf(acc[m][0][r] + bb0, 0.f);
        buf[ss*XMS + n0 + 16] = (f16)fmaxf(acc[m][1][r] + bb1, 0.f);
      }
    }
  }
  __syncthreads();

  // ---------------- Phase E: layer3 + sigmoid ----------------
  {
    f32x4 acc = {0.f,0.f,0.f,0.f};
#pragma unroll
    for (int kb=0; kb<4; ++kb){
      f16x8 a = *(const f16x8*)(buf + (w*16 + tr)*XMS + kb*32 + ko);
      f16x8 b = *(const f16x8*)(W3sw + (size_t)(kb*16 + tr)*32 + ko);
      acc = __builtin_amdgcn_mfma_f32_16x16x32_f16(a, b, acc, 0,0,0);
    }
    if (tr < 3){
      float bb = b3v[tr];
#pragma unroll
      for (int r=0;r<4;++r){
        float c = acc[r] + bb;
        out[(size_t)pmr[r]*4 + tr] = 1.f/(1.f + __expf(-c));
      }
    }
  }
}

extern "C" void kernel_launch(void* const* d_in, const int* in_sizes, int n_in,
                              void* d_out, int out_size, void* d_ws, size_t ws_size,
                              hipStream_t stream)
{
  const float* xin     = (const float*)d_in[0];
  const float* vmc_vec = (const float*)d_in[1];
  const float* vmc_mat = (const float*)d_in[2];
  const float* vmd_vec = (const float*)d_in[3];
  const float* vmd_mat = (const float*)d_in[4];
  const float* feat_w  = (const float*)d_in[5];
  const float* w1      = (const float*)d_in[6];
  const float* b1      = (const float*)d_in[7];
  const float* w2      = (const float*)d_in[8];
  const float* b2      = (const float*)d_in[9];
  const float* w3      = (const float*)d_in[10];
  const float* b3      = (const float*)d_in[11];
  float* out = (float*)d_out;

  char* ws = (char*)d_ws;
  f16*   Weff = (f16*)(ws + WOFF_WEFF);
  f16*   W1sw = (f16*)(ws + WOFF_W1SW);
  f16*   W2sw = (f16*)(ws + WOFF_W2SW);
  f16*   W3sw = (f16*)(ws + WOFF_W3SW);
  float* vd   = (float*)(ws + WOFF_VD);
  u32*   Tm   = (u32*)(ws + WOFF_TM);
  u32*   HT   = (u32*)(ws + WOFF_HT);
  u32*   Bt   = (u32*)(ws + WOFF_BT);
  float* xs   = (float*)(ws + WOFF_XS);
  u32*   perm = (u32*)(ws + WOFF_PERM);

  prep_k<<<64, 256, 0, stream>>>(feat_w, vmc_vec, vmd_vec, w1, w2, w3,
                                 Weff, W1sw, W2sw, W3sw, vd);
  pack_k<<<1800, 256, 0, stream>>>(vmc_mat, vmd_mat, Tm);

  if (ws_size >= (size_t)WS_NEED){
    hist_k<<<NBLK, 256, 0, stream>>>(xin, HT);
    scan_k<<<1, 1024, 0, stream>>>(HT, Bt);
    scatter_k<<<NBLK, 256, 0, stream>>>(xin, Bt, perm, xs);
    main_k<true><<<8192, 256, 0, stream>>>(xs, perm, Weff, W1sw, W2sw, W3sw, vd,
                                           (const uint4*)Tm, b1, b2, b3, out);
  } else {
    main_k<false><<<8192, 256, 0, stream>>>(xin, nullptr, Weff, W1sw, W2sw, W3sw, vd,
                                            (const uint4*)Tm, b1, b2, b3, out);
  }
}

// Round 10
// 307.893 us; speedup vs baseline: 1.4493x; 1.2135x over previous
//
#include <hip/hip_runtime.h>
#include <stdint.h>

typedef unsigned int u32;
typedef _Float16 f16;
typedef __attribute__((ext_vector_type(8))) _Float16 f16x8;
typedef __attribute__((ext_vector_type(4))) float f32x4;
typedef __attribute__((ext_vector_type(2))) float f32x2;

#define XMS 168   // f16 stride for LDS rows (336B)

#define NS     524288
#define NBIN   512
#define NBLK   512
#define SPB    1024

// ---- workspace layout (bytes) ----
#define WOFF_WEFF 0u          // 5*32*32*2    = 10240
#define WOFF_W1SW 10240u      // 5*128*32*2   = 40960
#define WOFF_W2SW 51200u      // 4*128*32*2   = 32768
#define WOFF_W3SW 83968u      // 4*16*32*2    = 4096
#define WOFF_VD   88064u      // 48*4         = 192
#define WOFF_TM   131072u     // 3*300*300*64 = 17280000 (fp8)
#define WOFF_H    17411072u   // 512*512*4    = 1048576
#define WOFF_BT   18459648u   // 512*512*4    = 1048576
#define WOFF_XS   19508224u   // 524288*24    = 12582912
#define WOFF_PERM 32091136u   // 524288*4     = 2097152
#define WS_NEED   34188288u

#define TBL_SCALE 64.0f
#define TBL_INV   (1.0f/64.0f)

// ================= prep: swizzled f16 weights (1/64 folded) =================
__global__ void prep_k(const float* __restrict__ feat_w,
                       const float* __restrict__ vmc_vec,
                       const float* __restrict__ vmd_vec,
                       const float* __restrict__ w1,
                       const float* __restrict__ w2,
                       const float* __restrict__ w3,
                       f16* __restrict__ Weff, f16* __restrict__ W1sw,
                       f16* __restrict__ W2sw, f16* __restrict__ W3sw,
                       float* __restrict__ vd)
{
  const int N_WEFF = 5120, N_W1 = 20480, N_W2 = 16384, N_W3 = 2048, N_VD = 48;
  const int total = N_WEFF + N_W1 + N_W2 + N_W3 + N_VD;
  for (int t = blockIdx.x*blockDim.x + threadIdx.x; t < total; t += gridDim.x*blockDim.x){
    if (t < N_WEFF){
      int kb = t >> 10, n = (t >> 5) & 31, kk = t & 31, k = kb*32 + kk;
      float v = 0.f;
      if (n < 27 && k < 144)
        v = feat_w[n*144 + k] * 0.5f*(vmc_vec[k*300+149] + vmc_vec[k*300+150]) * TBL_INV;
      Weff[t] = (f16)v;
    } else if (t < N_WEFF + N_W1){
      int u = t - N_WEFF;
      int kb = u >> 12, n = (u >> 5) & 127, kk = u & 31, k = kb*32 + kk;
      W1sw[u] = (f16)((k < 150) ? w1[n*150 + k] : 0.f);
    } else if (t < N_WEFF + N_W1 + N_W2){
      int u = t - N_WEFF - N_W1;
      int kb = u >> 12, n = (u >> 5) & 127, kk = u & 31, k = kb*32 + kk;
      W2sw[u] = (f16)w2[n*128 + k];
    } else if (t < N_WEFF + N_W1 + N_W2 + N_W3){
      int u = t - N_WEFF - N_W1 - N_W2;
      int kb = u >> 9, n = (u >> 5) & 15, kk = u & 31, k = kb*32 + kk;
      W3sw[u] = (f16)((n < 3) ? w3[n*128 + k] : 0.f);
    } else {
      int k = t - N_WEFF - N_W1 - N_W2 - N_W3;
      vd[k] = 0.5f*(vmd_vec[k*300+149] + vmd_vec[k*300+150]) * TBL_INV;
    }
  }
}

// ---- pack feature+density channels into Tm[plane][y][x][64ch] fp8*64 ----
__global__ void pack_k(const float* __restrict__ feat, const float* __restrict__ dens,
                       u32* __restrict__ dst)
{
  __shared__ float tile[48*304];
  int b = blockIdx.x;
  bool isf = b < 900;
  int bb = isf ? b : b - 900;
  int i = bb / 300, y = bb % 300;
  int C = isf ? 48 : 16;
  const float* sp = (isf ? feat : dens) + (size_t)i*C*90000 + (size_t)y*300;
  for (int t = threadIdx.x; t < C*300; t += 256){
    int r = t / 300, x = t - r*300;
    tile[r*304 + x] = sp[(size_t)r*90000 + x] * TBL_SCALE;
  }
  __syncthreads();
  u32* dp = dst + (size_t)(i*300 + y)*300*16 + (isf ? 0 : 12);
  int ng = C >> 2;
  for (int t = threadIdx.x; t < 300*ng; t += 256){
    int x = t / ng, cg = t - x*ng;
    int c = cg*4;
    u32 v = __builtin_amdgcn_cvt_pk_fp8_f32(tile[c*304+x],     tile[(c+1)*304+x], 0, false);
    v     = __builtin_amdgcn_cvt_pk_fp8_f32(tile[(c+2)*304+x], tile[(c+3)*304+x], v, true);
    dp[x*16 + cg] = v;
  }
}

// ================= 9-bit Morton counting sort (atomic-free global) =================
__device__ __forceinline__ u32 key9(float x, float y, float z){
  int a = min(7, max(0, (int)((x + 1.f)*4.f)));
  int b = min(7, max(0, (int)((y + 1.f)*4.f)));
  int c = min(7, max(0, (int)((z + 1.f)*4.f)));
  u32 r = 0;
#pragma unroll
  for (int i=0;i<3;++i)
    r |= (((u32)(a>>i)&1u)<<(3*i+2)) | (((u32)(b>>i)&1u)<<(3*i+1)) | (((u32)(c>>i)&1u)<<(3*i));
  return r;
}

// per-block LDS histogram -> H[blk][bin] (coalesced write)
__global__ __launch_bounds__(256)
void hist_k(const float* __restrict__ xin, u32* __restrict__ H)
{
  __shared__ u32 h[NBIN];
  for (int b = threadIdx.x; b < NBIN; b += 256) h[b] = 0u;
  __syncthreads();
  int base = blockIdx.x * SPB;
#pragma unroll
  for (int i = 0; i < SPB/256; ++i){
    int s = base + i*256 + threadIdx.x;
    const float* xp = xin + (size_t)s*6;
    atomicAdd(&h[key9(xp[0], xp[1], xp[2])], 1u);
  }
  __syncthreads();
  u32* Hp = H + (size_t)blockIdx.x*NBIN;
  for (int b = threadIdx.x; b < NBIN; b += 256) Hp[b] = h[b];
}

// one block, 512 threads (thread = bin): column sums + block scan + base emit.
// All H reads/writes are lane-coalesced (H[k*512 + t]).
__global__ __launch_bounds__(512, 1)
void scan_k(const u32* __restrict__ H, u32* __restrict__ Bt)
{
  __shared__ u32 s[NBIN];
  int t = threadIdx.x;
  u32 tot = 0;
  for (int k = 0; k < NBLK; ++k) tot += H[(size_t)k*NBIN + t];
  s[t] = tot;
  __syncthreads();
  for (int off=1; off<NBIN; off<<=1){
    u32 v = (t >= off) ? s[t-off] : 0u;
    __syncthreads();
    s[t] += v;
    __syncthreads();
  }
  u32 run = (t == 0) ? 0u : s[t-1];
  for (int k = 0; k < NBLK; ++k){
    Bt[(size_t)k*NBIN + t] = run;
    run += H[(size_t)k*NBIN + t];
  }
}

__global__ __launch_bounds__(256)
void scatter_k(const float* __restrict__ xin, const u32* __restrict__ Bt,
               u32* __restrict__ perm, float* __restrict__ xs)
{
  __shared__ u32 btl[NBIN];
  __shared__ u32 cnt[NBIN];
  for (int b = threadIdx.x; b < NBIN; b += 256){
    btl[b] = Bt[(size_t)blockIdx.x*NBIN + b];
    cnt[b] = 0u;
  }
  __syncthreads();
  int base = blockIdx.x * SPB;
#pragma unroll
  for (int i = 0; i < SPB/256; ++i){
    int s = base + i*256 + threadIdx.x;
    const float* sp = xin + (size_t)s*6;
    float v0=sp[0], v1=sp[1], v2=sp[2], v3=sp[3], v4=sp[4], v5=sp[5];
    u32 k = key9(v0, v1, v2);
    u32 pos = btl[k] + atomicAdd(&cnt[k], 1u);
    float* dp = xs + (size_t)pos*6;
    dp[0]=v0; dp[1]=v1; dp[2]=v2; dp[3]=v3; dp[4]=v4; dp[5]=v5;
    perm[pos] = (u32)s;
  }
}

__device__ __forceinline__ void decode16(uint4 q, float* o){
  f32x2 t;
  t = __builtin_amdgcn_cvt_pk_f32_fp8(q.x, false); o[0]=t[0];  o[1]=t[1];
  t = __builtin_amdgcn_cvt_pk_f32_fp8(q.x, true ); o[2]=t[0];  o[3]=t[1];
  t = __builtin_amdgcn_cvt_pk_f32_fp8(q.y, false); o[4]=t[0];  o[5]=t[1];
  t = __builtin_amdgcn_cvt_pk_f32_fp8(q.y, true ); o[6]=t[0];  o[7]=t[1];
  t = __builtin_amdgcn_cvt_pk_f32_fp8(q.z, false); o[8]=t[0];  o[9]=t[1];
  t = __builtin_amdgcn_cvt_pk_f32_fp8(q.z, true ); o[10]=t[0]; o[11]=t[1];
  t = __builtin_amdgcn_cvt_pk_f32_fp8(q.w, false); o[12]=t[0]; o[13]=t[1];
  t = __builtin_amdgcn_cvt_pk_f32_fp8(q.w, true ); o[14]=t[0]; o[15]=t[1];
}

// ======== wave-autonomous fused kernel: 16 samples/wave, ZERO barriers ========
template<bool SORTED>
__global__ __launch_bounds__(256, 4)
void main_k(const float* __restrict__ xs, const u32* __restrict__ perm,
            const f16* __restrict__ WeffSw, const f16* __restrict__ W1sw,
            const f16* __restrict__ W2sw, const f16* __restrict__ W3sw,
            const float* __restrict__ vd,
            const uint4* __restrict__ Tm,
            const float* __restrict__ b1v, const float* __restrict__ b2v,
            const float* __restrict__ b3v, float* __restrict__ out)
{
  // each wave owns rows [w*16, w*16+16): Xm -> X -> H1 -> H2 all in place
  __shared__ __align__(16) f16 buf[64*XMS];

  const int tid = threadIdx.x;
  const int l = tid & 63;
  const int w = tid >> 6;
  const int tile = SORTED ? ((blockIdx.x & 7)*1024 + (blockIdx.x >> 3)) : blockIdx.x;
  const size_t wb = (size_t)tile*64 + w*16;   // wave's first sample

  const int s16 = l & 15;       // sample within wave tile
  const int p   = l >> 4;       // 0..2 = plane, 3 = dirs/pad lane

  float dd0=0.f, dd1=0.f, dd2=0.f;
  float dacc = 0.f;

  // ---------------- gather (lanes 0..47), dirs+pad (lanes 48..63) ----------------
  if (p < 3){
    const float* xp = xs + (wb + s16)*6;
    float p0 = xp[0], p1 = xp[1], p2 = xp[2];
    float cx = (p==0)? p1 : ((p==1)? p2 : p0);
    float cy = (p==0)? p2 : ((p==1)? p0 : p1);
    float fx = (cx+1.f)*0.5f*299.f, fy = (cy+1.f)*0.5f*299.f;
    float x0f = floorf(fx), y0f = floorf(fy);
    int x0 = min(max((int)x0f,0),299), y0 = min(max((int)y0f,0),299);
    int x1 = min(x0+1,299), y1 = min(y0+1,299);
    float wx = fx-x0f, wy = fy-y0f;
    float w11 = wx*wy, w10 = wy - w11, w01 = wx - w11, w00 = 1.f - wx - wy + w11;

    const uint4* Tb = Tm + (size_t)p*90000*4;
    const uint4* r00 = Tb + (size_t)(y0*300+x0)*4;
    const uint4* r01 = Tb + (size_t)(y0*300+x1)*4;
    const uint4* r10 = Tb + (size_t)(y1*300+x0)*4;
    const uint4* r11 = Tb + (size_t)(y1*300+x1)*4;
    uint4 qa[4], qb[4], qc[4], qd[4];
#pragma unroll
    for (int c4=0;c4<4;++c4){ qa[c4]=r00[c4]; qb[c4]=r01[c4]; qc[c4]=r10[c4]; qd[c4]=r11[c4]; }

    float vdw[16];
#pragma unroll
    for (int j=0;j<16;++j) vdw[j] = vd[p*16 + j];

    f16* dstrow = buf + (w*16 + s16)*XMS + p*48;
#pragma unroll
    for (int c4=0;c4<4;++c4){
      float A[16],B[16],C[16],D[16];
      decode16(qa[c4],A); decode16(qb[c4],B); decode16(qc[c4],C); decode16(qd[c4],D);
      if (c4 < 3){
        f16x8 o0, o1;
#pragma unroll
        for (int j=0;j<8;++j)
          o0[j] = (f16)(w00*A[j] + w01*B[j] + w10*C[j] + w11*D[j]);
#pragma unroll
        for (int j=0;j<8;++j)
          o1[j] = (f16)(w00*A[8+j] + w01*B[8+j] + w10*C[8+j] + w11*D[8+j]);
        *(f16x8*)(dstrow + c4*16)     = o0;
        *(f16x8*)(dstrow + c4*16 + 8) = o1;
      } else {
#pragma unroll
        for (int j=0;j<16;++j)
          dacc += (w00*A[j] + w01*B[j] + w10*C[j] + w11*D[j]) * vdw[j];
      }
    }
  } else {
    // lanes 48..63: load dirs for sample s16; zero K-pad cols [144..160)
    const float* dp = xs + (wb + s16)*6 + 3;
    dd0 = dp[0]; dd1 = dp[1]; dd2 = dp[2];
    f16x8 z = 0;
    *(f16x8*)(buf + (w*16 + s16)*XMS + 144) = z;
    *(f16x8*)(buf + (w*16 + s16)*XMS + 152) = z;
  }

  // ---------------- density reduce across planes (shfl, no LDS) ----------------
  {
    float d1 = __shfl(dacc, l + 16);
    float d2 = __shfl(dacc, l + 32);
    if (l < 16){
      u32 pmd = SORTED ? perm[wb + l] : (u32)(wb + l);
      out[(size_t)pmd*4 + 3] = fmaxf(dacc + d1 + d2, 0.f);
    }
  }

  const int tr = l & 15;
  const int ko = (l >> 4) * 8;
  const int rbase = w*16 + (l>>4)*4;

  // output indices for this lane's 4 rows
  u32 pmr[4];
#pragma unroll
  for (int r=0;r<4;++r)
    pmr[r] = SORTED ? perm[wb + (l>>4)*4 + r] : (u32)(wb + (l>>4)*4 + r);

  // ---------------- fold MFMA (in-place Xm -> X) + PE ----------------
  {
    f32x4 fa0 = {0.f,0.f,0.f,0.f}, fa1 = {0.f,0.f,0.f,0.f};
    const f16* Arow = buf + (w*16 + tr)*XMS + ko;
#pragma unroll
    for (int kb=0; kb<5; ++kb){
      f16x8 a  = *(const f16x8*)(Arow + kb*32);
      f16x8 b0 = *(const f16x8*)(WeffSw + (size_t)(kb*32 + tr)*32 + ko);
      f16x8 b1 = *(const f16x8*)(WeffSw + (size_t)(kb*32 + 16 + tr)*32 + ko);
      fa0 = __builtin_amdgcn_mfma_f32_16x16x32_f16(a, b0, fa0, 0,0,0);
      fa1 = __builtin_amdgcn_mfma_f32_16x16x32_f16(a, b1, fa1, 0,0,0);
    }
    // pin all X writes after the fold's LDS reads (in-place, same-wave)
    __builtin_amdgcn_sched_barrier(0);
    asm volatile("" : "+v"(dd0), "+v"(dd1), "+v"(dd2) : "v"(fa0[0]));

#pragma unroll
    for (int nb=0; nb<2; ++nb){
      int f = nb*16 + tr;
      if (f < 27){
#pragma unroll
        for (int r=0;r<4;++r){
          float fv = nb ? fa1[r] : fa0[r];
          f16* Xr = buf + (rbase + r)*XMS;
          Xr[f] = (f16)fv;
          float a1 = 3.14159265358979f*fv;
          float a2 = 6.28318530717959f*fv;
          Xr[30+f]  = (f16)__sinf(a1);
          Xr[57+f]  = (f16)__cosf(a1);
          Xr[84+f]  = (f16)__sinf(a2);
          Xr[111+f] = (f16)__cosf(a2);
        }
      }
    }
    if (l >= 48){
      f16* Xr = buf + (w*16 + s16)*XMS;
      Xr[27]=(f16)dd0; Xr[28]=(f16)dd1; Xr[29]=(f16)dd2;
      float dv[3]={dd0,dd1,dd2};
#pragma unroll
      for (int j=0;j<3;++j){
        float a1=3.14159265358979f*dv[j], a2=6.28318530717959f*dv[j];
        Xr[138+j]=(f16)__sinf(a1);
        Xr[141+j]=(f16)__cosf(a1);
        Xr[144+j]=(f16)__sinf(a2);
        Xr[147+j]=(f16)__cosf(a2);
      }
    }
  }

  // ---------------- layer1: 16x160 * 160x128, in-place over X ----------------
  {
    f32x4 acc[8];
#pragma unroll
    for (int nb=0;nb<8;++nb) acc[nb] = (f32x4){0.f,0.f,0.f,0.f};
#pragma unroll
    for (int kb=0; kb<5; ++kb){
      f16x8 a = *(const f16x8*)(buf + (w*16 + tr)*XMS + kb*32 + ko);
#pragma unroll
      for (int nb=0;nb<8;++nb){
        f16x8 b = *(const f16x8*)(W1sw + (size_t)(kb*128 + nb*16 + tr)*32 + ko);
        acc[nb] = __builtin_amdgcn_mfma_f32_16x16x32_f16(a, b, acc[nb], 0,0,0);
      }
    }
    __builtin_amdgcn_sched_barrier(0);
#pragma unroll
    for (int nb=0;nb<8;++nb){
      float bb = b1v[nb*16 + tr];
#pragma unroll
      for (int r=0;r<4;++r)
        buf[(rbase + r)*XMS + nb*16 + tr] = (f16)fmaxf(acc[nb][r] + bb, 0.f);
    }
  }

  // ---------------- layer2: 16x128 * 128x128, in-place over H1 ----------------
  {
    f32x4 acc[8];
#pragma unroll
    for (int nb=0;nb<8;++nb) acc[nb] = (f32x4){0.f,0.f,0.f,0.f};
#pragma unroll
    for (int kb=0; kb<4; ++kb){
      f16x8 a = *(const f16x8*)(buf + (w*16 + tr)*XMS + kb*32 + ko);
#pragma unroll
      for (int nb=0;nb<8;++nb){
        f16x8 b = *(const f16x8*)(W2sw + (size_t)(kb*128 + nb*16 + tr)*32 + ko);
        acc[nb] = __builtin_amdgcn_mfma_f32_16x16x32_f16(a, b, acc[nb], 0,0,0);
      }
    }
    __builtin_amdgcn_sched_barrier(0);
#pragma unroll
    for (int nb=0;nb<8;++nb){
      float bb = b2v[nb*16 + tr];
#pragma unroll
      for (int r=0;r<4;++r)
        buf[(rbase + r)*XMS + nb*16 + tr] = (f16)fmaxf(acc[nb][r] + bb, 0.f);
    }
  }

  // ---------------- layer3 + sigmoid ----------------
  {
    f32x4 acc = {0.f,0.f,0.f,0.f};
#pragma unroll
    for (int kb=0; kb<4; ++kb){
      f16x8 a = *(const f16x8*)(buf + (w*16 + tr)*XMS + kb*32 + ko);
      f16x8 b = *(const f16x8*)(W3sw + (size_t)(kb*16 + tr)*32 + ko);
      acc = __builtin_amdgcn_mfma_f32_16x16x32_f16(a, b, acc, 0,0,0);
    }
    if (tr < 3){
      float bb = b3v[tr];
#pragma unroll
      for (int r=0;r<4;++r){
        float c = acc[r] + bb;
        out[(size_t)pmr[r]*4 + tr] = 1.f/(1.f + __expf(-c));
      }
    }
  }
}

extern "C" void kernel_launch(void* const* d_in, const int* in_sizes, int n_in,
                              void* d_out, int out_size, void* d_ws, size_t ws_size,
                              hipStream_t stream)
{
  const float* xin     = (const float*)d_in[0];
  const float* vmc_vec = (const float*)d_in[1];
  const float* vmc_mat = (const float*)d_in[2];
  const float* vmd_vec = (const float*)d_in[3];
  const float* vmd_mat = (const float*)d_in[4];
  const float* feat_w  = (const float*)d_in[5];
  const float* w1      = (const float*)d_in[6];
  const float* b1      = (const float*)d_in[7];
  const float* w2      = (const float*)d_in[8];
  const float* b2      = (const float*)d_in[9];
  const float* w3      = (const float*)d_in[10];
  const float* b3      = (const float*)d_in[11];
  float* out = (float*)d_out;

  char* ws = (char*)d_ws;
  f16*   Weff = (f16*)(ws + WOFF_WEFF);
  f16*   W1sw = (f16*)(ws + WOFF_W1SW);
  f16*   W2sw = (f16*)(ws + WOFF_W2SW);
  f16*   W3sw = (f16*)(ws + WOFF_W3SW);
  float* vd   = (float*)(ws + WOFF_VD);
  u32*   Tm   = (u32*)(ws + WOFF_TM);
  u32*   H    = (u32*)(ws + WOFF_H);
  u32*   Bt   = (u32*)(ws + WOFF_BT);
  float* xs   = (float*)(ws + WOFF_XS);
  u32*   perm = (u32*)(ws + WOFF_PERM);

  prep_k<<<64, 256, 0, stream>>>(feat_w, vmc_vec, vmd_vec, w1, w2, w3,
                                 Weff, W1sw, W2sw, W3sw, vd);
  pack_k<<<1800, 256, 0, stream>>>(vmc_mat, vmd_mat, Tm);

  if (ws_size >= (size_t)WS_NEED){
    hist_k<<<NBLK, 256, 0, stream>>>(xin, H);
    scan_k<<<1, 512, 0, stream>>>(H, Bt);
    scatter_k<<<NBLK, 256, 0, stream>>>(xin, Bt, perm, xs);
    main_k<true><<<8192, 256, 0, stream>>>(xs, perm, Weff, W1sw, W2sw, W3sw, vd,
                                           (const uint4*)Tm, b1, b2, b3, out);
  } else {
    main_k<false><<<8192, 256, 0, stream>>>(xin, nullptr, Weff, W1sw, W2sw, W3sw, vd,
                                            (const uint4*)Tm, b1, b2, b3, out);
  }
}

// Round 11
// 268.054 us; speedup vs baseline: 1.6647x; 1.1486x over previous
//
#include <hip/hip_runtime.h>
#include <stdint.h>

typedef unsigned int u32;
typedef _Float16 f16;
typedef __attribute__((ext_vector_type(8))) _Float16 f16x8;
typedef __attribute__((ext_vector_type(4))) float f32x4;
typedef __attribute__((ext_vector_type(2))) float f32x2;

#define XMS 168   // f16 stride for X rows (336B)
#define HS  136   // f16 stride for H1 / H2 rows (272B)

// ---- workspace layout (bytes) ----
#define WOFF_WEFF 0u          // 5*32*32*2    = 10240
#define WOFF_W1SW 10240u      // 5*128*32*2   = 40960
#define WOFF_W2SW 51200u      // 4*128*32*2   = 32768
#define WOFF_W3SW 83968u      // 4*16*32*2    = 4096
#define WOFF_VD   88064u      // 48*4         = 192
#define WOFF_TM   131072u     // 3*300*300*64 = 17280000 (fp8)
#define WS_NEED   17411072u

#define TBL_SCALE 64.0f
#define TBL_INV   (1.0f/64.0f)

// ================= prep: swizzled f16 weights (1/64 folded) =================
__global__ void prep_k(const float* __restrict__ feat_w,
                       const float* __restrict__ vmc_vec,
                       const float* __restrict__ vmd_vec,
                       const float* __restrict__ w1,
                       const float* __restrict__ w2,
                       const float* __restrict__ w3,
                       f16* __restrict__ Weff, f16* __restrict__ W1sw,
                       f16* __restrict__ W2sw, f16* __restrict__ W3sw,
                       float* __restrict__ vd)
{
  const int N_WEFF = 5120, N_W1 = 20480, N_W2 = 16384, N_W3 = 2048, N_VD = 48;
  const int total = N_WEFF + N_W1 + N_W2 + N_W3 + N_VD;
  for (int t = blockIdx.x*blockDim.x + threadIdx.x; t < total; t += gridDim.x*blockDim.x){
    if (t < N_WEFF){
      int kb = t >> 10, n = (t >> 5) & 31, kk = t & 31, k = kb*32 + kk;
      float v = 0.f;
      if (n < 27 && k < 144)
        v = feat_w[n*144 + k] * 0.5f*(vmc_vec[k*300+149] + vmc_vec[k*300+150]) * TBL_INV;
      Weff[t] = (f16)v;
    } else if (t < N_WEFF + N_W1){
      int u = t - N_WEFF;
      int kb = u >> 12, n = (u >> 5) & 127, kk = u & 31, k = kb*32 + kk;
      W1sw[u] = (f16)((k < 150) ? w1[n*150 + k] : 0.f);
    } else if (t < N_WEFF + N_W1 + N_W2){
      int u = t - N_WEFF - N_W1;
      int kb = u >> 12, n = (u >> 5) & 127, kk = u & 31, k = kb*32 + kk;
      W2sw[u] = (f16)w2[n*128 + k];
    } else if (t < N_WEFF + N_W1 + N_W2 + N_W3){
      int u = t - N_WEFF - N_W1 - N_W2;
      int kb = u >> 9, n = (u >> 5) & 15, kk = u & 31, k = kb*32 + kk;
      W3sw[u] = (f16)((n < 3) ? w3[n*128 + k] : 0.f);
    } else {
      int k = t - N_WEFF - N_W1 - N_W2 - N_W3;
      vd[k] = 0.5f*(vmd_vec[k*300+149] + vmd_vec[k*300+150]) * TBL_INV;
    }
  }
}

// ---- pack feature+density channels into Tm[plane][y][x][64ch] fp8*64 ----
__global__ void pack_k(const float* __restrict__ feat, const float* __restrict__ dens,
                       u32* __restrict__ dst)
{
  __shared__ float tile[48*304];
  int b = blockIdx.x;
  bool isf = b < 900;
  int bb = isf ? b : b - 900;
  int i = bb / 300, y = bb % 300;
  int C = isf ? 48 : 16;
  const float* sp = (isf ? feat : dens) + (size_t)i*C*90000 + (size_t)y*300;
  for (int t = threadIdx.x; t < C*300; t += 256){
    int r = t / 300, x = t - r*300;
    tile[r*304 + x] = sp[(size_t)r*90000 + x] * TBL_SCALE;
  }
  __syncthreads();
  u32* dp = dst + (size_t)(i*300 + y)*300*16 + (isf ? 0 : 12);
  int ng = C >> 2;
  for (int t = threadIdx.x; t < 300*ng; t += 256){
    int x = t / ng, cg = t - x*ng;
    int c = cg*4;
    u32 v = __builtin_amdgcn_cvt_pk_fp8_f32(tile[c*304+x],     tile[(c+1)*304+x], 0, false);
    v     = __builtin_amdgcn_cvt_pk_fp8_f32(tile[(c+2)*304+x], tile[(c+3)*304+x], v, true);
    dp[x*16 + cg] = v;
  }
}

__device__ __forceinline__ void decode16(uint4 q, float* o){
  f32x2 t;
  t = __builtin_amdgcn_cvt_pk_f32_fp8(q.x, false); o[0]=t[0];  o[1]=t[1];
  t = __builtin_amdgcn_cvt_pk_f32_fp8(q.x, true ); o[2]=t[0];  o[3]=t[1];
  t = __builtin_amdgcn_cvt_pk_f32_fp8(q.y, false); o[4]=t[0];  o[5]=t[1];
  t = __builtin_amdgcn_cvt_pk_f32_fp8(q.y, true ); o[6]=t[0];  o[7]=t[1];
  t = __builtin_amdgcn_cvt_pk_f32_fp8(q.z, false); o[8]=t[0];  o[9]=t[1];
  t = __builtin_amdgcn_cvt_pk_f32_fp8(q.z, true ); o[10]=t[0]; o[11]=t[1];
  t = __builtin_amdgcn_cvt_pk_f32_fp8(q.w, false); o[12]=t[0]; o[13]=t[1];
  t = __builtin_amdgcn_cvt_pk_f32_fp8(q.w, true ); o[14]=t[0]; o[15]=t[1];
}

// ======== fused main kernel: 2 tiles/block, software-pipelined gather ========
__global__ __launch_bounds__(256, 4)
void main_k(const float* __restrict__ xin,
            const f16* __restrict__ WeffSw, const f16* __restrict__ W1sw,
            const f16* __restrict__ W2sw, const f16* __restrict__ W3sw,
            const float* __restrict__ vd,
            const uint4* __restrict__ Tm,
            const float* __restrict__ b1v, const float* __restrict__ b2v,
            const float* __restrict__ b3v, float* __restrict__ out)
{
  __shared__ __align__(16) f16 buf[64*XMS];   // Xm -> X (in-place) -> H2 (stride HS)
  __shared__ __align__(16) f16 bufH[64*HS];   // H1
  __shared__ float dLds[192];

  const int tid = threadIdx.x;
  const int l = tid & 63;
  const int w = tid >> 6;
  const int tr = l & 15;
  const int ko = (l >> 4) * 8;
  const int rbase = w*16 + (l>>4)*4;

  const size_t base0 = (size_t)blockIdx.x * 128;
  const size_t base1 = base0 + 64;

  // prefetch state (one set, reused across tiles — disjoint live ranges)
  uint4 qa[4], qb[4], qc[4], qd[4];
  float w00=0.f, w01=0.f, w10=0.f, w11=0.f;

  auto load_pos = [&](size_t base, float& PX, float& PY, float& PZ,
                      float& D0, float& D1, float& D2){
    const float* xp = xin + (base + l)*6;
    PX = xp[0]; PY = xp[1]; PZ = xp[2];
    if (l < 16){
      const float* dp = xin + (base + w*16 + l)*6 + 3;
      D0 = dp[0]; D1 = dp[1]; D2 = dp[2];
    }
  };

  auto issue_corners = [&](float PX, float PY, float PZ){
    if (w < 3){
      float cx = (w==0)? PY : ((w==1)? PZ : PX);
      float cy = (w==0)? PZ : ((w==1)? PX : PY);
      float fx = (cx+1.f)*0.5f*299.f, fy = (cy+1.f)*0.5f*299.f;
      float x0f = floorf(fx), y0f = floorf(fy);
      int x0 = min(max((int)x0f,0),299), y0 = min(max((int)y0f,0),299);
      int x1 = min(x0+1,299), y1 = min(y0+1,299);
      float wx = fx-x0f, wy = fy-y0f;
      w11 = wx*wy; w10 = wy - w11; w01 = wx - w11; w00 = 1.f - wx - wy + w11;
      const uint4* Tb = Tm + (size_t)w*90000*4;
      const uint4* r00 = Tb + (size_t)(y0*300+x0)*4;
      const uint4* r01 = Tb + (size_t)(y0*300+x1)*4;
      const uint4* r10 = Tb + (size_t)(y1*300+x0)*4;
      const uint4* r11 = Tb + (size_t)(y1*300+x1)*4;
#pragma unroll
      for (int c4=0;c4<4;++c4){ qa[c4]=r00[c4]; qb[c4]=r01[c4]; qc[c4]=r10[c4]; qd[c4]=r11[c4]; }
    }
  };

  auto lerp_store = [&](){
    if (w < 3){
      float vdw[16];
#pragma unroll
      for (int j=0;j<16;++j) vdw[j] = vd[w*16 + j];
      f16* dstrow = buf + l*XMS + w*48;
      float dacc = 0.f;
#pragma unroll
      for (int c4=0;c4<4;++c4){
        float A[16],B[16],C[16],D[16];
        decode16(qa[c4],A); decode16(qb[c4],B); decode16(qc[c4],C); decode16(qd[c4],D);
        if (c4 < 3){
          f16x8 o0, o1;
#pragma unroll
          for (int j=0;j<8;++j)
            o0[j] = (f16)(w00*A[j] + w01*B[j] + w10*C[j] + w11*D[j]);
#pragma unroll
          for (int j=0;j<8;++j)
            o1[j] = (f16)(w00*A[8+j] + w01*B[8+j] + w10*C[8+j] + w11*D[8+j]);
          *(f16x8*)(dstrow + c4*16)     = o0;
          *(f16x8*)(dstrow + c4*16 + 8) = o1;
        } else {
#pragma unroll
          for (int j=0;j<16;++j)
            dacc += (w00*A[j] + w01*B[j] + w10*C[j] + w11*D[j]) * vdw[j];
        }
      }
      dLds[w*64 + l] = dacc;
    } else {
      f16x8 z = 0;
      *(f16x8*)(buf + l*XMS + 144) = z;
      *(f16x8*)(buf + l*XMS + 152) = z;
    }
  };

  auto fold_pe = [&](size_t base, float D0, float D1, float D2){
    if (w == 3){
      float ds = dLds[l] + dLds[64 + l] + dLds[128 + l];
      out[(base + l)*4 + 3] = fmaxf(ds, 0.f);
    }
    f32x4 fa0 = {0.f,0.f,0.f,0.f}, fa1 = {0.f,0.f,0.f,0.f};
    const f16* Arow = buf + (w*16 + tr)*XMS + ko;
#pragma unroll
    for (int kb=0; kb<5; ++kb){
      f16x8 a  = *(const f16x8*)(Arow + kb*32);
      f16x8 b0 = *(const f16x8*)(WeffSw + (size_t)(kb*32 + tr)*32 + ko);
      f16x8 b1 = *(const f16x8*)(WeffSw + (size_t)(kb*32 + 16 + tr)*32 + ko);
      fa0 = __builtin_amdgcn_mfma_f32_16x16x32_f16(a, b0, fa0, 0,0,0);
      fa1 = __builtin_amdgcn_mfma_f32_16x16x32_f16(a, b1, fa1, 0,0,0);
    }
    // pin all X writes after the fold's LDS reads (in-place, same-wave rows)
    __builtin_amdgcn_sched_barrier(0);
    asm volatile("" : "+v"(D0), "+v"(D1), "+v"(D2) : "v"(fa0[0]));

#pragma unroll
    for (int nb=0; nb<2; ++nb){
      int f = nb*16 + tr;
      if (f < 27){
#pragma unroll
        for (int r=0;r<4;++r){
          float fv = nb ? fa1[r] : fa0[r];
          f16* Xr = buf + (rbase + r)*XMS;
          Xr[f] = (f16)fv;
          float a1 = 3.14159265358979f*fv;
          float a2 = 6.28318530717959f*fv;
          Xr[30+f]  = (f16)__sinf(a1);
          Xr[57+f]  = (f16)__cosf(a1);
          Xr[84+f]  = (f16)__sinf(a2);
          Xr[111+f] = (f16)__cosf(a2);
        }
      }
    }
    if (l < 16){
      f16* Xr = buf + (w*16 + l)*XMS;
      Xr[27]=(f16)D0; Xr[28]=(f16)D1; Xr[29]=(f16)D2;
      float dv[3]={D0,D1,D2};
#pragma unroll
      for (int j=0;j<3;++j){
        float a1=3.14159265358979f*dv[j], a2=6.28318530717959f*dv[j];
        Xr[138+j]=(f16)__sinf(a1);
        Xr[141+j]=(f16)__cosf(a1);
        Xr[144+j]=(f16)__sinf(a2);
        Xr[147+j]=(f16)__cosf(a2);
      }
    }
  };

  // C/D use m-subtile passes (acc = 8 regs/pass) to keep VGPR under the 128 cap
  auto mlp = [&](size_t base){
    const int n0 = w*32 + tr;
    // ---- layer1: X(buf, XMS) -> H1(bufH, HS) ----
#pragma unroll
    for (int m=0; m<4; ++m){
      f32x4 a0 = {0.f,0.f,0.f,0.f}, a1v = {0.f,0.f,0.f,0.f};
#pragma unroll
      for (int kb=0; kb<5; ++kb){
        f16x8 b0 = *(const f16x8*)(W1sw + (size_t)(kb*128 + n0)*32 + ko);
        f16x8 b1 = *(const f16x8*)(W1sw + (size_t)(kb*128 + n0 + 16)*32 + ko);
        f16x8 a  = *(const f16x8*)(buf + (m*16 + tr)*XMS + kb*32 + ko);
        a0  = __builtin_amdgcn_mfma_f32_16x16x32_f16(a, b0, a0, 0,0,0);
        a1v = __builtin_amdgcn_mfma_f32_16x16x32_f16(a, b1, a1v, 0,0,0);
      }
      float bb0 = b1v[n0], bb1 = b1v[n0+16];
#pragma unroll
      for (int r=0;r<4;++r){
        int ss = m*16 + (l>>4)*4 + r;
        bufH[ss*HS + n0]      = (f16)fmaxf(a0[r] + bb0, 0.f);
        bufH[ss*HS + n0 + 16] = (f16)fmaxf(a1v[r] + bb1, 0.f);
      }
    }
    __syncthreads();
    // ---- layer2: H1(bufH) -> H2(buf, HS) ----
#pragma unroll
    for (int m=0; m<4; ++m){
      f32x4 a0 = {0.f,0.f,0.f,0.f}, a1v = {0.f,0.f,0.f,0.f};
#pragma unroll
      for (int kb=0; kb<4; ++kb){
        f16x8 b0 = *(const f16x8*)(W2sw + (size_t)(kb*128 + n0)*32 + ko);
        f16x8 b1 = *(const f16x8*)(W2sw + (size_t)(kb*128 + n0 + 16)*32 + ko);
        f16x8 a  = *(const f16x8*)(bufH + (m*16 + tr)*HS + kb*32 + ko);
        a0  = __builtin_amdgcn_mfma_f32_16x16x32_f16(a, b0, a0, 0,0,0);
        a1v = __builtin_amdgcn_mfma_f32_16x16x32_f16(a, b1, a1v, 0,0,0);
      }
      float bb0 = b2v[n0], bb1 = b2v[n0+16];
#pragma unroll
      for (int r=0;r<4;++r){
        int ss = m*16 + (l>>4)*4 + r;
        buf[ss*HS + n0]      = (f16)fmaxf(a0[r] + bb0, 0.f);
        buf[ss*HS + n0 + 16] = (f16)fmaxf(a1v[r] + bb1, 0.f);
      }
    }
    __syncthreads();
    // ---- layer3 + sigmoid ----
    {
      f32x4 acc = {0.f,0.f,0.f,0.f};
#pragma unroll
      for (int kb=0; kb<4; ++kb){
        f16x8 a = *(const f16x8*)(buf + (w*16 + tr)*HS + kb*32 + ko);
        f16x8 b = *(const f16x8*)(W3sw + (size_t)(kb*16 + tr)*32 + ko);
        acc = __builtin_amdgcn_mfma_f32_16x16x32_f16(a, b, acc, 0,0,0);
      }
      if (tr < 3){
        float bb = b3v[tr];
#pragma unroll
        for (int r=0;r<4;++r){
          float c = acc[r] + bb;
          out[(base + rbase + r)*4 + tr] = 1.f/(1.f + __expf(-c));
        }
      }
    }
  };

  // ================= pipelined 2-tile schedule =================
  float px0,py0,pz0, e00=0.f,e01=0.f,e02=0.f;
  float px1,py1,pz1, e10=0.f,e11=0.f,e12=0.f;

  load_pos(base0, px0,py0,pz0, e00,e01,e02);
  issue_corners(px0,py0,pz0);
  lerp_store();                       // tile0 Xm -> LDS
  __syncthreads();
  load_pos(base1, px1,py1,pz1, e10,e11,e12);   // t1 positions fly during fold
  fold_pe(base0, e00,e01,e02);
  __syncthreads();
  issue_corners(px1,py1,pz1);         // t1 corners fly during C/D/E of t0
  mlp(base0);
  __syncthreads();                    // E's buf reads done before overwrite
  lerp_store();                       // tile1 (corners have landed)
  __syncthreads();
  fold_pe(base1, e10,e11,e12);
  __syncthreads();
  mlp(base1);
}

extern "C" void kernel_launch(void* const* d_in, const int* in_sizes, int n_in,
                              void* d_out, int out_size, void* d_ws, size_t ws_size,
                              hipStream_t stream)
{
  const float* xin     = (const float*)d_in[0];
  const float* vmc_vec = (const float*)d_in[1];
  const float* vmc_mat = (const float*)d_in[2];
  const float* vmd_vec = (const float*)d_in[3];
  const float* vmd_mat = (const float*)d_in[4];
  const float* feat_w  = (const float*)d_in[5];
  const float* w1      = (const float*)d_in[6];
  const float* b1      = (const float*)d_in[7];
  const float* w2      = (const float*)d_in[8];
  const float* b2      = (const float*)d_in[9];
  const float* w3      = (const float*)d_in[10];
  const float* b3      = (const float*)d_in[11];
  float* out = (float*)d_out;

  char* ws = (char*)d_ws;
  f16*   Weff = (f16*)(ws + WOFF_WEFF);
  f16*   W1sw = (f16*)(ws + WOFF_W1SW);
  f16*   W2sw = (f16*)(ws + WOFF_W2SW);
  f16*   W3sw = (f16*)(ws + WOFF_W3SW);
  float* vd   = (float*)(ws + WOFF_VD);
  u32*   Tm   = (u32*)(ws + WOFF_TM);

  prep_k<<<64, 256, 0, stream>>>(feat_w, vmc_vec, vmd_vec, w1, w2, w3,
                                 Weff, W1sw, W2sw, W3sw, vd);
  pack_k<<<1800, 256, 0, stream>>>(vmc_mat, vmd_mat, Tm);

  main_k<<<4096, 256, 0, stream>>>(xin, Weff, W1sw, W2sw, W3sw, vd,
                                   (const uint4*)Tm, b1, b2, b3, out);
}

// Round 12
// 185.205 us; speedup vs baseline: 2.4094x; 1.4473x over previous
//
#include <hip/hip_runtime.h>
#include <stdint.h>

typedef unsigned int u32;
typedef _Float16 f16;
typedef __attribute__((ext_vector_type(8))) _Float16 f16x8;
typedef __attribute__((ext_vector_type(4))) float f32x4;
typedef __attribute__((ext_vector_type(2))) float f32x2;

#define XMS 168   // f16 stride for X rows (336B)
#define HS  136   // f16 stride for H1 / H2 rows (272B)

#define NS      524288
#define NBIN_S  64        // 2 bits per axis
#define NBLK_S  128
#define SPB_S   4096      // samples per sort block

// ---- workspace layout (bytes) ----
#define WOFF_WEFF 0u          // 5*32*32*2    = 10240
#define WOFF_W1SW 10240u      // 5*128*32*2   = 40960
#define WOFF_W2SW 51200u      // 4*128*32*2   = 32768
#define WOFF_W3SW 83968u      // 4*16*32*2    = 4096
#define WOFF_VD   88064u      // 48*4         = 192
#define WOFF_TM   131072u     // 3*300*300*64 = 17280000 (fp8)
#define WOFF_H    17411072u   // 128*64*4     = 32768
#define WOFF_BT   17443840u   // 128*64*4     = 32768
#define WOFF_XS   17476608u   // 524288*24    = 12582912
#define WOFF_PERM 30059520u   // 524288*4     = 2097152
#define WS_NEED   32156672u

#define TBL_SCALE 64.0f
#define TBL_INV   (1.0f/64.0f)

// ================= prep: swizzled f16 weights (1/64 folded) =================
__global__ void prep_k(const float* __restrict__ feat_w,
                       const float* __restrict__ vmc_vec,
                       const float* __restrict__ vmd_vec,
                       const float* __restrict__ w1,
                       const float* __restrict__ w2,
                       const float* __restrict__ w3,
                       f16* __restrict__ Weff, f16* __restrict__ W1sw,
                       f16* __restrict__ W2sw, f16* __restrict__ W3sw,
                       float* __restrict__ vd)
{
  const int N_WEFF = 5120, N_W1 = 20480, N_W2 = 16384, N_W3 = 2048, N_VD = 48;
  const int total = N_WEFF + N_W1 + N_W2 + N_W3 + N_VD;
  for (int t = blockIdx.x*blockDim.x + threadIdx.x; t < total; t += gridDim.x*blockDim.x){
    if (t < N_WEFF){
      int kb = t >> 10, n = (t >> 5) & 31, kk = t & 31, k = kb*32 + kk;
      float v = 0.f;
      if (n < 27 && k < 144)
        v = feat_w[n*144 + k] * 0.5f*(vmc_vec[k*300+149] + vmc_vec[k*300+150]) * TBL_INV;
      Weff[t] = (f16)v;
    } else if (t < N_WEFF + N_W1){
      int u = t - N_WEFF;
      int kb = u >> 12, n = (u >> 5) & 127, kk = u & 31, k = kb*32 + kk;
      W1sw[u] = (f16)((k < 150) ? w1[n*150 + k] : 0.f);
    } else if (t < N_WEFF + N_W1 + N_W2){
      int u = t - N_WEFF - N_W1;
      int kb = u >> 12, n = (u >> 5) & 127, kk = u & 31, k = kb*32 + kk;
      W2sw[u] = (f16)w2[n*128 + k];
    } else if (t < N_WEFF + N_W1 + N_W2 + N_W3){
      int u = t - N_WEFF - N_W1 - N_W2;
      int kb = u >> 9, n = (u >> 5) & 15, kk = u & 31, k = kb*32 + kk;
      W3sw[u] = (f16)((n < 3) ? w3[n*128 + k] : 0.f);
    } else {
      int k = t - N_WEFF - N_W1 - N_W2 - N_W3;
      vd[k] = 0.5f*(vmd_vec[k*300+149] + vmd_vec[k*300+150]) * TBL_INV;
    }
  }
}

// ---- pack feature+density channels into Tm[plane][y][x][64ch] fp8*64 ----
__global__ void pack_k(const float* __restrict__ feat, const float* __restrict__ dens,
                       u32* __restrict__ dst)
{
  __shared__ float tile[48*304];
  int b = blockIdx.x;
  bool isf = b < 900;
  int bb = isf ? b : b - 900;
  int i = bb / 300, y = bb % 300;
  int C = isf ? 48 : 16;
  const float* sp = (isf ? feat : dens) + (size_t)i*C*90000 + (size_t)y*300;
  for (int t = threadIdx.x; t < C*300; t += 256){
    int r = t / 300, x = t - r*300;
    tile[r*304 + x] = sp[(size_t)r*90000 + x] * TBL_SCALE;
  }
  __syncthreads();
  u32* dp = dst + (size_t)(i*300 + y)*300*16 + (isf ? 0 : 12);
  int ng = C >> 2;
  for (int t = threadIdx.x; t < 300*ng; t += 256){
    int x = t / ng, cg = t - x*ng;
    int c = cg*4;
    u32 v = __builtin_amdgcn_cvt_pk_fp8_f32(tile[c*304+x],     tile[(c+1)*304+x], 0, false);
    v     = __builtin_amdgcn_cvt_pk_fp8_f32(tile[(c+2)*304+x], tile[(c+3)*304+x], v, true);
    dp[x*16 + cg] = v;
  }
}

// ================= 6-bit Morton counting sort (cheap) =================
__device__ __forceinline__ u32 key6(float x, float y, float z){
  int a = min(3, max(0, (int)((x + 1.f)*2.f)));
  int b = min(3, max(0, (int)((y + 1.f)*2.f)));
  int c = min(3, max(0, (int)((z + 1.f)*2.f)));
  u32 r = 0;
#pragma unroll
  for (int i=0;i<2;++i)
    r |= (((u32)(a>>i)&1u)<<(3*i+2)) | (((u32)(b>>i)&1u)<<(3*i+1)) | (((u32)(c>>i)&1u)<<(3*i));
  return r;
}

// per-block LDS histogram -> H[blk][bin]
__global__ __launch_bounds__(256)
void hist_k(const float* __restrict__ xin, u32* __restrict__ H)
{
  __shared__ u32 h[NBIN_S];
  if (threadIdx.x < NBIN_S) h[threadIdx.x] = 0u;
  __syncthreads();
  int base = blockIdx.x * SPB_S;
#pragma unroll
  for (int i = 0; i < SPB_S/256; ++i){
    int s = base + i*256 + threadIdx.x;
    const float* xp = xin + (size_t)s*6;
    atomicAdd(&h[key6(xp[0], xp[1], xp[2])], 1u);
  }
  __syncthreads();
  if (threadIdx.x < NBIN_S)
    H[(size_t)blockIdx.x*NBIN_S + threadIdx.x] = h[threadIdx.x];
}

// one wave, thread t = bin: column sum -> block scan -> per-(blk,bin) base
__global__ __launch_bounds__(64, 1)
void scan_k(const u32* __restrict__ H, u32* __restrict__ Bt)
{
  __shared__ u32 s[NBIN_S];
  int t = threadIdx.x;
  u32 tot = 0;
  for (int k = 0; k < NBLK_S; ++k) tot += H[(size_t)k*NBIN_S + t];
  s[t] = tot;
  __syncthreads();
  for (int off=1; off<NBIN_S; off<<=1){
    u32 v = (t >= off) ? s[t-off] : 0u;
    __syncthreads();
    s[t] += v;
    __syncthreads();
  }
  u32 run = (t == 0) ? 0u : s[t-1];
  for (int k = 0; k < NBLK_S; ++k){
    Bt[(size_t)k*NBIN_S + t] = run;
    run += H[(size_t)k*NBIN_S + t];
  }
}

__global__ __launch_bounds__(256)
void scatter_k(const float* __restrict__ xin, const u32* __restrict__ Bt,
               u32* __restrict__ perm, float* __restrict__ xs)
{
  __shared__ u32 btl[NBIN_S];
  __shared__ u32 cnt[NBIN_S];
  if (threadIdx.x < NBIN_S){
    btl[threadIdx.x] = Bt[(size_t)blockIdx.x*NBIN_S + threadIdx.x];
    cnt[threadIdx.x] = 0u;
  }
  __syncthreads();
  int base = blockIdx.x * SPB_S;
#pragma unroll
  for (int i = 0; i < SPB_S/256; ++i){
    int s = base + i*256 + threadIdx.x;
    const float* sp = xin + (size_t)s*6;
    float v0=sp[0], v1=sp[1], v2=sp[2], v3=sp[3], v4=sp[4], v5=sp[5];
    u32 k = key6(v0, v1, v2);
    u32 pos = btl[k] + atomicAdd(&cnt[k], 1u);
    float* dp = xs + (size_t)pos*6;
    dp[0]=v0; dp[1]=v1; dp[2]=v2; dp[3]=v3; dp[4]=v4; dp[5]=v5;
    perm[pos] = (u32)s;
  }
}

__device__ __forceinline__ void decode16(uint4 q, float* o){
  f32x2 t;
  t = __builtin_amdgcn_cvt_pk_f32_fp8(q.x, false); o[0]=t[0];  o[1]=t[1];
  t = __builtin_amdgcn_cvt_pk_f32_fp8(q.x, true ); o[2]=t[0];  o[3]=t[1];
  t = __builtin_amdgcn_cvt_pk_f32_fp8(q.y, false); o[4]=t[0];  o[5]=t[1];
  t = __builtin_amdgcn_cvt_pk_f32_fp8(q.y, true ); o[6]=t[0];  o[7]=t[1];
  t = __builtin_amdgcn_cvt_pk_f32_fp8(q.z, false); o[8]=t[0];  o[9]=t[1];
  t = __builtin_amdgcn_cvt_pk_f32_fp8(q.z, true ); o[10]=t[0]; o[11]=t[1];
  t = __builtin_amdgcn_cvt_pk_f32_fp8(q.w, false); o[12]=t[0]; o[13]=t[1];
  t = __builtin_amdgcn_cvt_pk_f32_fp8(q.w, true ); o[14]=t[0]; o[15]=t[1];
}

// ======== fused main kernel (R7 structure: 2 LDS buffers, 4 blocks/CU) ========
template<bool SORTED>
__global__ __launch_bounds__(256, 4)
void main_k(const float* __restrict__ xs, const u32* __restrict__ perm,
            const f16* __restrict__ WeffSw, const f16* __restrict__ W1sw,
            const f16* __restrict__ W2sw, const f16* __restrict__ W3sw,
            const float* __restrict__ vd,
            const uint4* __restrict__ Tm,
            const float* __restrict__ b1v, const float* __restrict__ b2v,
            const float* __restrict__ b3v, float* __restrict__ out)
{
  __shared__ __align__(16) f16 buf[64*XMS];   // Xm -> X (in-place) -> H2 (stride HS)
  __shared__ __align__(16) f16 bufH[64*HS];   // H1
  __shared__ float dLds[192];

  const int tid = threadIdx.x;
  const int l = tid & 63;
  const int w = tid >> 6;

  // XCD-chunked swizzle: each XCD owns a contiguous Morton range
  const int tile = SORTED ? ((blockIdx.x & 7)*1024 + (blockIdx.x >> 3)) : blockIdx.x;
  const size_t base = (size_t)tile*64;

  const float* xp = xs + (base + l)*6;
  float p0 = xp[0], p1 = xp[1], p2 = xp[2];

  // output indices (original sample ids)
  u32 pmL = SORTED ? perm[base + l] : (u32)(base + l);
  const int ssb = w*16 + (l>>4)*4;
  u32 pmr[4];
#pragma unroll
  for (int r=0;r<4;++r)
    pmr[r] = SORTED ? perm[base + ssb + r] : (u32)(base + ssb + r);

  // preload dirs for the row this (wave, lane<16) owns in Phase B
  float dd0=0.f, dd1=0.f, dd2=0.f;
  if (l < 16){
    const float* dp = xs + (base + w*16 + l)*6 + 3;
    dd0 = dp[0]; dd1 = dp[1]; dd2 = dp[2];
  }

  // ---------------- Phase A: sampling (waves 0..2, one plane each) ----------------
  if (w < 3){
    float cx = (w==0)? p1 : ((w==1)? p2 : p0);
    float cy = (w==0)? p2 : ((w==1)? p0 : p1);
    float fx = (cx+1.f)*0.5f*299.f, fy = (cy+1.f)*0.5f*299.f;
    float x0f = floorf(fx), y0f = floorf(fy);
    int x0 = min(max((int)x0f,0),299), y0 = min(max((int)y0f,0),299);
    int x1 = min(x0+1,299), y1 = min(y0+1,299);
    float wx = fx-x0f, wy = fy-y0f;
    float w11 = wx*wy, w10 = wy - w11, w01 = wx - w11, w00 = 1.f - wx - wy + w11;

    const uint4* Tb = Tm + (size_t)w*90000*4;
    const uint4* r00 = Tb + (size_t)(y0*300+x0)*4;
    const uint4* r01 = Tb + (size_t)(y0*300+x1)*4;
    const uint4* r10 = Tb + (size_t)(y1*300+x0)*4;
    const uint4* r11 = Tb + (size_t)(y1*300+x1)*4;
    uint4 qa[4], qb[4], qc[4], qd[4];
#pragma unroll
    for (int c4=0;c4<4;++c4){ qa[c4]=r00[c4]; qb[c4]=r01[c4]; qc[c4]=r10[c4]; qd[c4]=r11[c4]; }

    float vdw[16];
#pragma unroll
    for (int j=0;j<16;++j) vdw[j] = vd[w*16 + j];

    f16* dstrow = buf + l*XMS + w*48;
    float dacc = 0.f;
#pragma unroll
    for (int c4=0;c4<4;++c4){
      float A[16],B[16],C[16],D[16];
      decode16(qa[c4],A); decode16(qb[c4],B); decode16(qc[c4],C); decode16(qd[c4],D);
      if (c4 < 3){
        f16x8 o0, o1;
#pragma unroll
        for (int j=0;j<8;++j)
          o0[j] = (f16)(w00*A[j] + w01*B[j] + w10*C[j] + w11*D[j]);
#pragma unroll
        for (int j=0;j<8;++j)
          o1[j] = (f16)(w00*A[8+j] + w01*B[8+j] + w10*C[8+j] + w11*D[8+j]);
        *(f16x8*)(dstrow + c4*16)     = o0;
        *(f16x8*)(dstrow + c4*16 + 8) = o1;
      } else {
#pragma unroll
        for (int j=0;j<16;++j)
          dacc += (w00*A[j] + w01*B[j] + w10*C[j] + w11*D[j]) * vdw[j];
      }
    }
    dLds[w*64 + l] = dacc;
  } else {
    // wave 3: zero K-pad cols [144..160)
    f16x8 z = 0;
    *(f16x8*)(buf + l*XMS + 144) = z;
    *(f16x8*)(buf + l*XMS + 152) = z;
  }
  __syncthreads();

  const int tr = l & 15;
  const int ko = (l >> 4) * 8;

  // ---------------- Phase B: fold MFMA (in-place Xm -> X) + PE ----------------
  {
    if (w == 3){
      float ds = dLds[l] + dLds[64 + l] + dLds[128 + l];
      out[(size_t)pmL*4 + 3] = fmaxf(ds, 0.f);
    }
    f32x4 fa0 = {0.f,0.f,0.f,0.f}, fa1 = {0.f,0.f,0.f,0.f};
    const f16* Arow = buf + (w*16 + tr)*XMS + ko;
#pragma unroll
    for (int kb=0; kb<5; ++kb){
      f16x8 a  = *(const f16x8*)(Arow + kb*32);
      f16x8 b0 = *(const f16x8*)(WeffSw + (size_t)(kb*32 + tr)*32 + ko);
      f16x8 b1 = *(const f16x8*)(WeffSw + (size_t)(kb*32 + 16 + tr)*32 + ko);
      fa0 = __builtin_amdgcn_mfma_f32_16x16x32_f16(a, b0, fa0, 0,0,0);
      fa1 = __builtin_amdgcn_mfma_f32_16x16x32_f16(a, b1, fa1, 0,0,0);
    }
    __builtin_amdgcn_sched_barrier(0);
    asm volatile("" : "+v"(dd0), "+v"(dd1), "+v"(dd2) : "v"(fa0[0]));

#pragma unroll
    for (int nb=0; nb<2; ++nb){
      int f = nb*16 + tr;
      if (f < 27){
#pragma unroll
        for (int r=0;r<4;++r){
          float fv = nb ? fa1[r] : fa0[r];
          f16* Xr = buf + (ssb + r)*XMS;
          Xr[f] = (f16)fv;
          float a1 = 3.14159265358979f*fv;
          float s1 = __sinf(a1), c1 = __cosf(a1);
          Xr[30+f]  = (f16)s1;
          Xr[57+f]  = (f16)c1;
          Xr[84+f]  = (f16)(2.f*s1*c1);          // sin(2a)
          Xr[111+f] = (f16)(1.f - 2.f*s1*s1);    // cos(2a)
        }
      }
    }
    if (l < 16){
      f16* Xr = buf + (w*16 + l)*XMS;
      Xr[27]=(f16)dd0; Xr[28]=(f16)dd1; Xr[29]=(f16)dd2;
      float dv[3]={dd0,dd1,dd2};
#pragma unroll
      for (int j=0;j<3;++j){
        float a1 = 3.14159265358979f*dv[j];
        float s1 = __sinf(a1), c1 = __cosf(a1);
        Xr[138+j]=(f16)s1;
        Xr[141+j]=(f16)c1;
        Xr[144+j]=(f16)(2.f*s1*c1);
        Xr[147+j]=(f16)(1.f - 2.f*s1*s1);
      }
    }
  }
  __syncthreads();

  // ---------------- Phase C: layer1 (64x160 * 160x128) -> bufH ----------------
  {
    f32x4 acc[4][2];
#pragma unroll
    for (int m=0;m<4;++m){ acc[m][0]=(f32x4){0.f,0.f,0.f,0.f}; acc[m][1]=(f32x4){0.f,0.f,0.f,0.f}; }
    const int n0 = w*32 + tr;
#pragma unroll
    for (int kb=0; kb<5; ++kb){
      f16x8 b0 = *(const f16x8*)(W1sw + (size_t)(kb*128 + n0)*32 + ko);
      f16x8 b1 = *(const f16x8*)(W1sw + (size_t)(kb*128 + n0 + 16)*32 + ko);
#pragma unroll
      for (int m=0;m<4;++m){
        f16x8 a = *(const f16x8*)(buf + (m*16 + tr)*XMS + kb*32 + ko);
        acc[m][0] = __builtin_amdgcn_mfma_f32_16x16x32_f16(a, b0, acc[m][0], 0,0,0);
        acc[m][1] = __builtin_amdgcn_mfma_f32_16x16x32_f16(a, b1, acc[m][1], 0,0,0);
      }
    }
    float bb0 = b1v[n0], bb1 = b1v[n0+16];
#pragma unroll
    for (int m=0;m<4;++m){
#pragma unroll
      for (int r=0;r<4;++r){
        int ss = m*16 + (l>>4)*4 + r;
        bufH[ss*HS + n0]      = (f16)fmaxf(acc[m][0][r] + bb0, 0.f);
        bufH[ss*HS + n0 + 16] = (f16)fmaxf(acc[m][1][r] + bb1, 0.f);
      }
    }
  }
  __syncthreads();

  // ---------------- Phase D: layer2 (64x128 * 128x128), H2 overlays buf ----------------
  {
    f32x4 acc[4][2];
#pragma unroll
    for (int m=0;m<4;++m){ acc[m][0]=(f32x4){0.f,0.f,0.f,0.f}; acc[m][1]=(f32x4){0.f,0.f,0.f,0.f}; }
    const int n0 = w*32 + tr;
#pragma unroll
    for (int kb=0; kb<4; ++kb){
      f16x8 b0 = *(const f16x8*)(W2sw + (size_t)(kb*128 + n0)*32 + ko);
      f16x8 b1 = *(const f16x8*)(W2sw + (size_t)(kb*128 + n0 + 16)*32 + ko);
#pragma unroll
      for (int m=0;m<4;++m){
        f16x8 a = *(const f16x8*)(bufH + (m*16 + tr)*HS + kb*32 + ko);
        acc[m][0] = __builtin_amdgcn_mfma_f32_16x16x32_f16(a, b0, acc[m][0], 0,0,0);
        acc[m][1] = __builtin_amdgcn_mfma_f32_16x16x32_f16(a, b1, acc[m][1], 0,0,0);
      }
    }
    float bb0 = b2v[n0], bb1 = b2v[n0+16];
#pragma unroll
    for (int m=0;m<4;++m){
#pragma unroll
      for (int r=0;r<4;++r){
        int ss = m*16 + (l>>4)*4 + r;
        buf[ss*HS + n0]      = (f16)fmaxf(acc[m][0][r] + bb0, 0.f);
        buf[ss*HS + n0 + 16] = (f16)fmaxf(acc[m][1][r] + bb1, 0.f);
      }
    }
  }
  __syncthreads();

  // ---------------- Phase E: layer3 + sigmoid ----------------
  {
    f32x4 acc = {0.f,0.f,0.f,0.f};
#pragma unroll
    for (int kb=0; kb<4; ++kb){
      f16x8 a = *(const f16x8*)(buf + (w*16 + tr)*HS + kb*32 + ko);
      f16x8 b = *(const f16x8*)(W3sw + (size_t)(kb*16 + tr)*32 + ko);
      acc = __builtin_amdgcn_mfma_f32_16x16x32_f16(a, b, acc, 0,0,0);
    }
    if (tr < 3){
      float bb = b3v[tr];
#pragma unroll
      for (int r=0;r<4;++r){
        float c = acc[r] + bb;
        out[(size_t)pmr[r]*4 + tr] = 1.f/(1.f + __expf(-c));
      }
    }
  }
}

extern "C" void kernel_launch(void* const* d_in, const int* in_sizes, int n_in,
                              void* d_out, int out_size, void* d_ws, size_t ws_size,
                              hipStream_t stream)
{
  const float* xin     = (const float*)d_in[0];
  const float* vmc_vec = (const float*)d_in[1];
  const float* vmc_mat = (const float*)d_in[2];
  const float* vmd_vec = (const float*)d_in[3];
  const float* vmd_mat = (const float*)d_in[4];
  const float* feat_w  = (const float*)d_in[5];
  const float* w1      = (const float*)d_in[6];
  const float* b1      = (const float*)d_in[7];
  const float* w2      = (const float*)d_in[8];
  const float* b2      = (const float*)d_in[9];
  const float* w3      = (const float*)d_in[10];
  const float* b3      = (const float*)d_in[11];
  float* out = (float*)d_out;

  char* ws = (char*)d_ws;
  f16*   Weff = (f16*)(ws + WOFF_WEFF);
  f16*   W1sw = (f16*)(ws + WOFF_W1SW);
  f16*   W2sw = (f16*)(ws + WOFF_W2SW);
  f16*   W3sw = (f16*)(ws + WOFF_W3SW);
  float* vd   = (float*)(ws + WOFF_VD);
  u32*   Tm   = (u32*)(ws + WOFF_TM);
  u32*   H    = (u32*)(ws + WOFF_H);
  u32*   Bt   = (u32*)(ws + WOFF_BT);
  float* xs   = (float*)(ws + WOFF_XS);
  u32*   perm = (u32*)(ws + WOFF_PERM);

  prep_k<<<64, 256, 0, stream>>>(feat_w, vmc_vec, vmd_vec, w1, w2, w3,
                                 Weff, W1sw, W2sw, W3sw, vd);
  pack_k<<<1800, 256, 0, stream>>>(vmc_mat, vmd_mat, Tm);

  if (ws_size >= (size_t)WS_NEED){
    hist_k<<<NBLK_S, 256, 0, stream>>>(xin, H);
    scan_k<<<1, 64, 0, stream>>>(H, Bt);
    scatter_k<<<NBLK_S, 256, 0, stream>>>(xin, Bt, perm, xs);
    main_k<true><<<8192, 256, 0, stream>>>(xs, perm, Weff, W1sw, W2sw, W3sw, vd,
                                           (const uint4*)Tm, b1, b2, b3, out);
  } else {
    main_k<false><<<8192, 256, 0, stream>>>(xin, nullptr, Weff, W1sw, W2sw, W3sw, vd,
                                            (const uint4*)Tm, b1, b2, b3, out);
  }
}